// Round 6
// baseline (737.188 us; speedup 1.0000x reference)
//
#include <hip/hip_runtime.h>

// L2 self-attention. Inputs/outputs FP32 (per reference); compute in bf16
// MFMA with fp32 accumulate. B=2 N=2048 D=1024 H=16 hd=64.
// fp32->bf16 conversion happens inline at GEMM staging. Q/K/Vt intermediates
// are bf16 in d_ws (adaptive head-group size G, demand G*802816 B, >=1.53MB).
// att is fp32 directly in d_out (4096x1024 floats == out_size); final
// projection is IN-PLACE over d_out (row-banded, LDS snapshot, race-free).

typedef __attribute__((ext_vector_type(8))) short sh8;   // 8 bf16 (4 VGPRs)
typedef __attribute__((ext_vector_type(4))) short sh4;   // 4 bf16 (2 VGPRs)
typedef __attribute__((ext_vector_type(4))) float f4;    // 4 fp32

__device__ __forceinline__ float bf2f(short s) {
  union { unsigned u; float f; } c;
  c.u = ((unsigned)(unsigned short)s) << 16;
  return c.f;
}
__device__ __forceinline__ short f2bf(float f) {
  union { float f; unsigned u; } c;
  c.f = f;
  unsigned u = c.u + 0x7FFFu + ((c.u >> 16) & 1u);  // RNE
  return (short)(u >> 16);
}
__device__ __forceinline__ sh8 pack8(f4 a, f4 b) {
  sh8 r;
  r[0] = f2bf(a[0]); r[1] = f2bf(a[1]); r[2] = f2bf(a[2]); r[3] = f2bf(a[3]);
  r[4] = f2bf(b[0]); r[5] = f2bf(b[1]); r[6] = f2bf(b[2]); r[7] = f2bf(b[3]);
  return r;
}

// ---------------------------------------------------------------------------
// QKV projection for a group of G heads. C[m,c] = sum_k X[m,k]*W[c,k]+bias.
// blockIdx.x in [0, 3*G/2): which = /nblkP, col-block = %nblkP (128 cols).
// Qp,Kp stored bf16 [hl][n][64]; Vtp bf16 transposed [hl][64][n], hl in [0,G).
// ---------------------------------------------------------------------------
__global__ __launch_bounds__(256) void gemm_qkvp(
    const float* __restrict__ X,   // batch rows: 2048 x 1024 fp32
    const float* __restrict__ Wq, const float* __restrict__ Bq,
    const float* __restrict__ Wk, const float* __restrict__ Bk,
    const float* __restrict__ Wv, const float* __restrict__ Bv,
    short* __restrict__ Qp, short* __restrict__ Kp, short* __restrict__ Vtp,
    int w0, int nblkP) {
  __shared__ short As[128 * 32];
  __shared__ short Bs[128 * 32];
  const int t = threadIdx.x;
  const int wave = t >> 6;
  const int lane = t & 63;
  const int l15 = lane & 15;
  const int quad = lane >> 4;
  const int m0 = blockIdx.y * 128;                 // [0,2048)
  const int which = blockIdx.x / nblkP;            // 0=Q 1=K 2=V
  const int nblk = blockIdx.x % nblkP;
  const int n0l = nblk * 128;                      // group-local col offset
  const int wrow0 = w0 + n0l;                      // W row offset (global)
  const float* W = (which == 0) ? Wq : ((which == 1) ? Wk : Wv);
  const float* Bias = (which == 0) ? Bq : ((which == 1) ? Bk : Bv);
  const int wm = (wave & 1) * 64;
  const int wn = (wave >> 1) * 64;

  f4 acc[4][4];
#pragma unroll
  for (int i = 0; i < 4; ++i)
#pragma unroll
    for (int j = 0; j < 4; ++j) acc[i][j] = (f4){0.f, 0.f, 0.f, 0.f};

  // staging: thread t covers tile elems {i*2048 + t*8} of the 128x32 k-slice
  // (row i*64 + (t>>2), cols (t&3)*8..+7). fp32 loads, bf16 LDS stores.
  const float* ag = X + (size_t)(m0 + (t >> 2)) * 1024 + (t & 3) * 8;
  const float* bg = W + (size_t)(wrow0 + (t >> 2)) * 1024 + (t & 3) * 8;

  for (int kt = 0; kt < 1024; kt += 32) {
    const sh8 a0 = pack8(*(const f4*)(ag + kt), *(const f4*)(ag + kt + 4));
    const sh8 a1 =
        pack8(*(const f4*)(ag + 65536 + kt), *(const f4*)(ag + 65536 + kt + 4));
    const sh8 b0 = pack8(*(const f4*)(bg + kt), *(const f4*)(bg + kt + 4));
    const sh8 b1 =
        pack8(*(const f4*)(bg + 65536 + kt), *(const f4*)(bg + 65536 + kt + 4));
    __syncthreads();  // prior iter's LDS reads complete
    *(sh8*)(As + t * 8) = a0;
    *(sh8*)(As + 2048 + t * 8) = a1;
    *(sh8*)(Bs + t * 8) = b0;
    *(sh8*)(Bs + 2048 + t * 8) = b1;
    __syncthreads();
    sh8 af[4], bf[4];
#pragma unroll
    for (int i = 0; i < 4; ++i) {
      af[i] = *(const sh8*)(As + (wm + i * 16 + l15) * 32 + quad * 8);
      bf[i] = *(const sh8*)(Bs + (wn + i * 16 + l15) * 32 + quad * 8);
    }
#pragma unroll
    for (int i = 0; i < 4; ++i)
#pragma unroll
      for (int j = 0; j < 4; ++j)
        acc[i][j] =
            __builtin_amdgcn_mfma_f32_16x16x32_bf16(af[i], bf[j], acc[i][j], 0, 0, 0);
  }

  // epilogue: C[m = quad*4+r (+offsets)][col = l15 (+offsets)]
#pragma unroll
  for (int j = 0; j < 4; ++j) {
    const int ngl = n0l + wn + j * 16 + l15;  // group-local col [0, G*64)
    const float bias = Bias[w0 + ngl];
    const int hl = ngl >> 6;   // group-local head
    const int d = ngl & 63;
#pragma unroll
    for (int i = 0; i < 4; ++i) {
#pragma unroll
      for (int r = 0; r < 4; ++r) {
        const int m = m0 + wm + i * 16 + quad * 4 + r;  // [0,2048)
        const short o = f2bf(acc[i][j][r] + bias);
        if (which == 0)
          Qp[((size_t)hl * 2048 + m) * 64 + d] = o;
        else if (which == 1)
          Kp[((size_t)hl * 2048 + m) * 64 + d] = o;
        else
          Vtp[((size_t)hl * 64 + d) * 2048 + m] = o;
      }
    }
  }
}

// ---------------------------------------------------------------------------
// Sums of squares of bf16-rounded Q and K rows (consistent with MFMA dot).
// R rows per tensor (R = G*2048), Q then K.
// ---------------------------------------------------------------------------
__global__ __launch_bounds__(256) void sumsq(const short* __restrict__ Qp,
                                             const short* __restrict__ Kp,
                                             float* __restrict__ q2a,
                                             float* __restrict__ k2a, int R) {
  const int tid = blockIdx.x * 256 + threadIdx.x;  // [0, 2R)
  const bool isQ = tid < R;
  const int r = isQ ? tid : tid - R;
  const short* p = (isQ ? Qp : Kp) + (size_t)r * 64;
  float s = 0.f;
#pragma unroll
  for (int i = 0; i < 8; ++i) {
    sh8 v = *(const sh8*)(p + i * 8);
#pragma unroll
    for (int j = 0; j < 8; ++j) {
      float f = bf2f(v[j]);
      s = fmaf(f, f, s);
    }
  }
  (isQ ? q2a : k2a)[r] = s;
}

// ---------------------------------------------------------------------------
// Flash attention for one head group. Block = 4 waves; wave owns 16 queries.
// S^T = MFMA(A=K, B=Q): C row=key(quad*4+r), col=query(l15) == A-operand
// layout of P for mfma 16x16x16 PV. O C-layout: row=query, col=vdim chunk.
// Writes fp32 att cols [col0 + hy*64, +64) of attB (this batch's d_out rows).
// ---------------------------------------------------------------------------
__global__ __launch_bounds__(256) void attn(
    const short* __restrict__ Qp, const short* __restrict__ Kp,
    const short* __restrict__ Vtp, const float* __restrict__ q2a,
    const float* __restrict__ k2a, float* __restrict__ attB, int col0) {
  const int t = threadIdx.x;
  const int wave = t >> 6;
  const int lane = t & 63;
  const int l15 = lane & 15;
  const int quad = lane >> 4;
  const int hy = blockIdx.y;  // group-local head
  const int qt = blockIdx.x;  // 0..31
  const int qrow = qt * 64 + wave * 16 + l15;
  const size_t base = (size_t)hy * 2048;

  const short* qp = Qp + (base + qrow) * 64 + quad * 8;
  const sh8 qf0 = *(const sh8*)qp;
  const sh8 qf1 = *(const sh8*)(qp + 32);
  const float q2 = q2a[base + qrow];

  float m_run = -1e30f, l_run = 0.f;
  f4 o0 = (f4){0.f, 0.f, 0.f, 0.f}, o1 = o0, o2 = o0, o3 = o0;

  const short* kbase = Kp + (base + l15) * 64 + quad * 8;
  const float* k2p = k2a + base + quad * 4;
  const short* vbase = Vtp + ((size_t)hy * 64 + l15) * 2048 + quad * 4;

  for (int j0 = 0; j0 < 2048; j0 += 16) {
    const sh8 kf0 = *(const sh8*)(kbase + (size_t)j0 * 64);
    const sh8 kf1 = *(const sh8*)(kbase + (size_t)j0 * 64 + 32);
    f4 st = (f4){0.f, 0.f, 0.f, 0.f};
    st = __builtin_amdgcn_mfma_f32_16x16x32_bf16(kf0, qf0, st, 0, 0, 0);
    st = __builtin_amdgcn_mfma_f32_16x16x32_bf16(kf1, qf1, st, 0, 0, 0);
    const f4 k2v = *(const f4*)(k2p + j0);

    float sc[4];
#pragma unroll
    for (int r = 0; r < 4; ++r) {
      float d2 = q2 + k2v[r] - 2.f * st[r];
      d2 = fmaxf(d2, 1e-12f);
      sc[r] = -sqrtf(d2);
    }
    float tm = fmaxf(fmaxf(sc[0], sc[1]), fmaxf(sc[2], sc[3]));
    tm = fmaxf(tm, __shfl_xor(tm, 16));
    tm = fmaxf(tm, __shfl_xor(tm, 32));
    const float m_new = fmaxf(m_run, tm);
    const float alpha = __expf(m_run - m_new);
    float p[4], ps;
#pragma unroll
    for (int r = 0; r < 4; ++r) p[r] = __expf(sc[r] - m_new);
    ps = (p[0] + p[1]) + (p[2] + p[3]);
    ps += __shfl_xor(ps, 16);
    ps += __shfl_xor(ps, 32);
    l_run = l_run * alpha + ps;
    m_run = m_new;

    sh4 pf;
#pragma unroll
    for (int r = 0; r < 4; ++r) pf[r] = f2bf(p[r]);

    const sh4 vf0 = *(const sh4*)(vbase + j0);
    const sh4 vf1 = *(const sh4*)(vbase + 16 * 2048 + j0);
    const sh4 vf2 = *(const sh4*)(vbase + 32 * 2048 + j0);
    const sh4 vf3 = *(const sh4*)(vbase + 48 * 2048 + j0);

    // alpha for O rows (query = quad*4+r); state lives on lanes 0..15
    const float a0 = __shfl(alpha, quad * 4 + 0);
    const float a1 = __shfl(alpha, quad * 4 + 1);
    const float a2 = __shfl(alpha, quad * 4 + 2);
    const float a3 = __shfl(alpha, quad * 4 + 3);
    o0[0] *= a0; o0[1] *= a1; o0[2] *= a2; o0[3] *= a3;
    o1[0] *= a0; o1[1] *= a1; o1[2] *= a2; o1[3] *= a3;
    o2[0] *= a0; o2[1] *= a1; o2[2] *= a2; o2[3] *= a3;
    o3[0] *= a0; o3[1] *= a1; o3[2] *= a2; o3[3] *= a3;

    o0 = __builtin_amdgcn_mfma_f32_16x16x16bf16_1k(pf, vf0, o0, 0, 0, 0);
    o1 = __builtin_amdgcn_mfma_f32_16x16x16bf16_1k(pf, vf1, o1, 0, 0, 0);
    o2 = __builtin_amdgcn_mfma_f32_16x16x16bf16_1k(pf, vf2, o2, 0, 0, 0);
    o3 = __builtin_amdgcn_mfma_f32_16x16x16bf16_1k(pf, vf3, o3, 0, 0, 0);
  }

  const float il0 = 1.f / __shfl(l_run, quad * 4 + 0);
  const float il1 = 1.f / __shfl(l_run, quad * 4 + 1);
  const float il2 = 1.f / __shfl(l_run, quad * 4 + 2);
  const float il3 = 1.f / __shfl(l_run, quad * 4 + 3);

  const int rowbase = qt * 64 + wave * 16 + quad * 4;
  float* op = attB + (size_t)rowbase * 1024 + col0 + hy * 64 + l15;
  const f4* oc[4] = {&o0, &o1, &o2, &o3};
  const float il[4] = {il0, il1, il2, il3};
#pragma unroll
  for (int c = 0; c < 4; ++c)
#pragma unroll
    for (int r = 0; r < 4; ++r)
      op[(size_t)r * 1024 + c * 16] = (*oc[c])[r] * il[r];
}

// ---------------------------------------------------------------------------
// IN-PLACE output projection over d_out (fp32): A = att (4096x1024 fp32),
// Out[m,n] = sum_k A[m,k]*Wo[n,k] + bo[n], overwritten in place.
// Block owns rows [m0,m0+16): snapshots them (bf16) to LDS k-chunked; stores
// happen only after the full K-loop, so in-place is race-free.
// LDS row stride 264 (+8 pad) breaks the 16-way bank conflict.
// ---------------------------------------------------------------------------
__global__ __launch_bounds__(256) void outproj_inplace(
    float* __restrict__ AO, const float* __restrict__ W,
    const float* __restrict__ Bias) {
  __shared__ short attS[16 * 264];
  const int t = threadIdx.x;
  const int wave = t >> 6;
  const int lane = t & 63;
  const int l15 = lane & 15;
  const int quad = lane >> 4;
  const int m0 = blockIdx.x * 16;
  const int n0w = wave * 256;

  f4 acc[16];
#pragma unroll
  for (int i = 0; i < 16; ++i) acc[i] = (f4){0.f, 0.f, 0.f, 0.f};

  for (int kc = 0; kc < 4; ++kc) {  // k-chunks of 256
    __syncthreads();
#pragma unroll
    for (int i = 0; i < 2; ++i) {
      const int e = i * 2048 + t * 8;
      const int row = e >> 8;
      const int col = e & 255;
      const float* src = AO + (size_t)(m0 + row) * 1024 + kc * 256 + col;
      *(sh8*)(attS + row * 264 + col) =
          pack8(*(const f4*)src, *(const f4*)(src + 4));
    }
    __syncthreads();
    for (int ktl = 0; ktl < 256; ktl += 32) {
      const sh8 af = *(const sh8*)(attS + l15 * 264 + ktl + quad * 8);
      const int kt = kc * 256 + ktl;
#pragma unroll
      for (int nf = 0; nf < 16; ++nf) {
        const float* wp = W + (size_t)(n0w + nf * 16 + l15) * 1024 + kt + quad * 8;
        const sh8 bf = pack8(*(const f4*)wp, *(const f4*)(wp + 4));
        acc[nf] = __builtin_amdgcn_mfma_f32_16x16x32_bf16(af, bf, acc[nf], 0, 0, 0);
      }
    }
  }
  __syncthreads();  // all snapshot reads done block-wide before stores

#pragma unroll
  for (int nf = 0; nf < 16; ++nf) {
    const int n = n0w + nf * 16 + l15;
    const float bias = Bias[n];
#pragma unroll
    for (int r = 0; r < 4; ++r) {
      const int m = m0 + quad * 4 + r;
      AO[(size_t)m * 1024 + n] = acc[nf][r] + bias;
    }
  }
}

// ---------------------------------------------------------------------------
extern "C" void kernel_launch(void* const* d_in, const int* in_sizes, int n_in,
                              void* d_out, int out_size, void* d_ws,
                              size_t ws_size, hipStream_t stream) {
  const float* x = (const float*)d_in[0];
  const float* wq = (const float*)d_in[1];
  const float* bq = (const float*)d_in[2];
  const float* wk = (const float*)d_in[3];
  const float* bk = (const float*)d_in[4];
  const float* wv = (const float*)d_in[5];
  const float* bv = (const float*)d_in[6];
  const float* wo = (const float*)d_in[7];
  const float* bo = (const float*)d_in[8];
  float* out = (float*)d_out;

  // Head-group size G from ws_size. Per-head: Q 256KB + K 256KB + Vt 256KB
  // + q2 8KB + k2 8KB = 802816 B. G=2 -> 1.53 MB demand.
  int G = 16;
  while (G > 2 && (size_t)G * 802816ULL > ws_size) G >>= 1;

  short* Qp = (short*)d_ws;                 // G*131072 bf16
  short* Kp = Qp + (size_t)G * 131072;
  short* Vtp = Kp + (size_t)G * 131072;
  float* q2 = (float*)(Vtp + (size_t)G * 131072);  // G*2048 fp32
  float* k2 = q2 + (size_t)G * 2048;

  const int groups = 16 / G;
  for (int b = 0; b < 2; ++b) {
    const float* xb = x + (size_t)b * 2097152;
    float* attB = out + (size_t)b * 2097152;
    for (int g = 0; g < groups; ++g) {
      gemm_qkvp<<<dim3(3 * (G / 2), 16), 256, 0, stream>>>(
          xb, wq, bq, wk, bk, wv, bv, Qp, Kp, Vtp, g * G * 64, G / 2);
      sumsq<<<16 * G, 256, 0, stream>>>(Qp, Kp, q2, k2, G * 2048);
      attn<<<dim3(32, G), 256, 0, stream>>>(Qp, Kp, Vtp, q2, k2, attB,
                                            g * G * 64);
    }
  }
  outproj_inplace<<<256, 256, 0, stream>>>(out, wo, bo);
}

// Round 7
// 575.273 us; speedup vs baseline: 1.2815x; 1.2815x over previous
//
#include <hip/hip_runtime.h>

// L2 self-attention. Inputs/outputs FP32; compute bf16 MFMA, fp32 accumulate.
// B=2 N=2048 D=1024 H=16 hd=64.
// Fast path (ws >= 20.25MB): per-batch qkv -> sumsq -> attn (att bf16 in ws)
// then one m97-style tiled GEMM att@Wo^T -> d_out (no in-place hazard).
// Fallback (small ws): exact round-6 path (adaptive G, in-place outproj).

typedef __attribute__((ext_vector_type(8))) short sh8;   // 8 bf16 (4 VGPRs)
typedef __attribute__((ext_vector_type(4))) short sh4;   // 4 bf16 (2 VGPRs)
typedef __attribute__((ext_vector_type(4))) float f4;    // 4 fp32

__device__ __forceinline__ float bf2f(short s) {
  union { unsigned u; float f; } c;
  c.u = ((unsigned)(unsigned short)s) << 16;
  return c.f;
}
__device__ __forceinline__ short f2bf(float f) {
  union { float f; unsigned u; } c;
  c.f = f;
  unsigned u = c.u + 0x7FFFu + ((c.u >> 16) & 1u);  // RNE
  return (short)(u >> 16);
}
__device__ __forceinline__ sh8 pack8(f4 a, f4 b) {
  sh8 r;
  r[0] = f2bf(a[0]); r[1] = f2bf(a[1]); r[2] = f2bf(a[2]); r[3] = f2bf(a[3]);
  r[4] = f2bf(b[0]); r[5] = f2bf(b[1]); r[6] = f2bf(b[2]); r[7] = f2bf(b[3]);
  return r;
}

// async global->LDS, 16B per lane; LDS dest = wave-uniform base + lane*16
#define GLDS16(g, l)                                                      \
  __builtin_amdgcn_global_load_lds(                                       \
      (__attribute__((address_space(1))) void*)(void*)(g),                \
      (__attribute__((address_space(3))) void*)(void*)(l), 16, 0, 0)

// ---------------------------------------------------------------------------
// QKV projection for a group of G heads. C[m,c] = sum_k X[m,k]*W[c,k]+bias.
// blockIdx.x in [0, 3*nblkP): which = /nblkP, col-block = %nblkP (128 cols).
// Qp,Kp stored bf16 [hl][n][64]; Vtp bf16 transposed [hl][64][n].
// ---------------------------------------------------------------------------
__global__ __launch_bounds__(256) void gemm_qkvp(
    const float* __restrict__ X,   // batch rows: 2048 x 1024 fp32
    const float* __restrict__ Wq, const float* __restrict__ Bq,
    const float* __restrict__ Wk, const float* __restrict__ Bk,
    const float* __restrict__ Wv, const float* __restrict__ Bv,
    short* __restrict__ Qp, short* __restrict__ Kp, short* __restrict__ Vtp,
    int w0, int nblkP) {
  __shared__ short As[128 * 32];
  __shared__ short Bs[128 * 32];
  const int t = threadIdx.x;
  const int wave = t >> 6;
  const int lane = t & 63;
  const int l15 = lane & 15;
  const int quad = lane >> 4;
  const int m0 = blockIdx.y * 128;                 // [0,2048)
  const int which = blockIdx.x / nblkP;            // 0=Q 1=K 2=V
  const int nblk = blockIdx.x % nblkP;
  const int n0l = nblk * 128;                      // group-local col offset
  const int wrow0 = w0 + n0l;                      // W row offset (global)
  const float* W = (which == 0) ? Wq : ((which == 1) ? Wk : Wv);
  const float* Bias = (which == 0) ? Bq : ((which == 1) ? Bk : Bv);
  const int wm = (wave & 1) * 64;
  const int wn = (wave >> 1) * 64;

  f4 acc[4][4];
#pragma unroll
  for (int i = 0; i < 4; ++i)
#pragma unroll
    for (int j = 0; j < 4; ++j) acc[i][j] = (f4){0.f, 0.f, 0.f, 0.f};

  const float* ag = X + (size_t)(m0 + (t >> 2)) * 1024 + (t & 3) * 8;
  const float* bg = W + (size_t)(wrow0 + (t >> 2)) * 1024 + (t & 3) * 8;

  for (int kt = 0; kt < 1024; kt += 32) {
    const sh8 a0 = pack8(*(const f4*)(ag + kt), *(const f4*)(ag + kt + 4));
    const sh8 a1 =
        pack8(*(const f4*)(ag + 65536 + kt), *(const f4*)(ag + 65536 + kt + 4));
    const sh8 b0 = pack8(*(const f4*)(bg + kt), *(const f4*)(bg + kt + 4));
    const sh8 b1 =
        pack8(*(const f4*)(bg + 65536 + kt), *(const f4*)(bg + 65536 + kt + 4));
    __syncthreads();  // prior iter's LDS reads complete
    *(sh8*)(As + t * 8) = a0;
    *(sh8*)(As + 2048 + t * 8) = a1;
    *(sh8*)(Bs + t * 8) = b0;
    *(sh8*)(Bs + 2048 + t * 8) = b1;
    __syncthreads();
    sh8 af[4], bf[4];
#pragma unroll
    for (int i = 0; i < 4; ++i) {
      af[i] = *(const sh8*)(As + (wm + i * 16 + l15) * 32 + quad * 8);
      bf[i] = *(const sh8*)(Bs + (wn + i * 16 + l15) * 32 + quad * 8);
    }
#pragma unroll
    for (int i = 0; i < 4; ++i)
#pragma unroll
      for (int j = 0; j < 4; ++j)
        acc[i][j] =
            __builtin_amdgcn_mfma_f32_16x16x32_bf16(af[i], bf[j], acc[i][j], 0, 0, 0);
  }

#pragma unroll
  for (int j = 0; j < 4; ++j) {
    const int ngl = n0l + wn + j * 16 + l15;  // group-local col
    const float bias = Bias[w0 + ngl];
    const int hl = ngl >> 6;
    const int d = ngl & 63;
#pragma unroll
    for (int i = 0; i < 4; ++i) {
#pragma unroll
      for (int r = 0; r < 4; ++r) {
        const int m = m0 + wm + i * 16 + quad * 4 + r;
        const short o = f2bf(acc[i][j][r] + bias);
        if (which == 0)
          Qp[((size_t)hl * 2048 + m) * 64 + d] = o;
        else if (which == 1)
          Kp[((size_t)hl * 2048 + m) * 64 + d] = o;
        else
          Vtp[((size_t)hl * 64 + d) * 2048 + m] = o;
      }
    }
  }
}

// ---------------------------------------------------------------------------
// Sums of squares of bf16-rounded Q and K rows. R rows per tensor.
// ---------------------------------------------------------------------------
__global__ __launch_bounds__(256) void sumsq(const short* __restrict__ Qp,
                                             const short* __restrict__ Kp,
                                             float* __restrict__ q2a,
                                             float* __restrict__ k2a, int R) {
  const int tid = blockIdx.x * 256 + threadIdx.x;
  const bool isQ = tid < R;
  const int r = isQ ? tid : tid - R;
  const short* p = (isQ ? Qp : Kp) + (size_t)r * 64;
  float s = 0.f;
#pragma unroll
  for (int i = 0; i < 8; ++i) {
    sh8 v = *(const sh8*)(p + i * 8);
#pragma unroll
    for (int j = 0; j < 8; ++j) {
      float f = bf2f(v[j]);
      s = fmaf(f, f, s);
    }
  }
  (isQ ? q2a : k2a)[r] = s;
}

// ---------------------------------------------------------------------------
// Flash attention for one head group. Block = 4 waves; wave owns 16 queries.
// S^T = MFMA(A=K, B=Q): C row=key(quad*4+r), col=query(l15) == A-operand
// layout of P for mfma 16x16x16 PV. O C-layout: row=query, col=vdim chunk.
// BF16OUT=1: store bf16 att into attH. BF16OUT=0: fp32 into attF (fallback).
// ---------------------------------------------------------------------------
template <int BF16OUT>
__global__ __launch_bounds__(256) void attn_t(
    const short* __restrict__ Qp, const short* __restrict__ Kp,
    const short* __restrict__ Vtp, const float* __restrict__ q2a,
    const float* __restrict__ k2a, float* __restrict__ attF,
    short* __restrict__ attH, int col0) {
  const int t = threadIdx.x;
  const int wave = t >> 6;
  const int lane = t & 63;
  const int l15 = lane & 15;
  const int quad = lane >> 4;
  const int hy = blockIdx.y;  // group-local head
  const int qt = blockIdx.x;  // 0..31
  const int qrow = qt * 64 + wave * 16 + l15;
  const size_t base = (size_t)hy * 2048;

  const short* qp = Qp + (base + qrow) * 64 + quad * 8;
  const sh8 qf0 = *(const sh8*)qp;
  const sh8 qf1 = *(const sh8*)(qp + 32);
  const float q2 = q2a[base + qrow];

  float m_run = -1e30f, l_run = 0.f;
  f4 o0 = (f4){0.f, 0.f, 0.f, 0.f}, o1 = o0, o2 = o0, o3 = o0;

  const short* kbase = Kp + (base + l15) * 64 + quad * 8;
  const float* k2p = k2a + base + quad * 4;
  const short* vbase = Vtp + ((size_t)hy * 64 + l15) * 2048 + quad * 4;

  for (int j0 = 0; j0 < 2048; j0 += 16) {
    const sh8 kf0 = *(const sh8*)(kbase + (size_t)j0 * 64);
    const sh8 kf1 = *(const sh8*)(kbase + (size_t)j0 * 64 + 32);
    f4 st = (f4){0.f, 0.f, 0.f, 0.f};
    st = __builtin_amdgcn_mfma_f32_16x16x32_bf16(kf0, qf0, st, 0, 0, 0);
    st = __builtin_amdgcn_mfma_f32_16x16x32_bf16(kf1, qf1, st, 0, 0, 0);
    const f4 k2v = *(const f4*)(k2p + j0);

    float sc[4];
#pragma unroll
    for (int r = 0; r < 4; ++r) {
      float d2 = q2 + k2v[r] - 2.f * st[r];
      d2 = fmaxf(d2, 1e-12f);
      sc[r] = -sqrtf(d2);
    }
    float tm = fmaxf(fmaxf(sc[0], sc[1]), fmaxf(sc[2], sc[3]));
    tm = fmaxf(tm, __shfl_xor(tm, 16));
    tm = fmaxf(tm, __shfl_xor(tm, 32));
    const float m_new = fmaxf(m_run, tm);
    const float alpha = __expf(m_run - m_new);
    float p[4], ps;
#pragma unroll
    for (int r = 0; r < 4; ++r) p[r] = __expf(sc[r] - m_new);
    ps = (p[0] + p[1]) + (p[2] + p[3]);
    ps += __shfl_xor(ps, 16);
    ps += __shfl_xor(ps, 32);
    l_run = l_run * alpha + ps;
    m_run = m_new;

    sh4 pf;
#pragma unroll
    for (int r = 0; r < 4; ++r) pf[r] = f2bf(p[r]);

    const sh4 vf0 = *(const sh4*)(vbase + j0);
    const sh4 vf1 = *(const sh4*)(vbase + 16 * 2048 + j0);
    const sh4 vf2 = *(const sh4*)(vbase + 32 * 2048 + j0);
    const sh4 vf3 = *(const sh4*)(vbase + 48 * 2048 + j0);

    const float a0 = __shfl(alpha, quad * 4 + 0);
    const float a1 = __shfl(alpha, quad * 4 + 1);
    const float a2 = __shfl(alpha, quad * 4 + 2);
    const float a3 = __shfl(alpha, quad * 4 + 3);
    o0[0] *= a0; o0[1] *= a1; o0[2] *= a2; o0[3] *= a3;
    o1[0] *= a0; o1[1] *= a1; o1[2] *= a2; o1[3] *= a3;
    o2[0] *= a0; o2[1] *= a1; o2[2] *= a2; o2[3] *= a3;
    o3[0] *= a0; o3[1] *= a1; o3[2] *= a2; o3[3] *= a3;

    o0 = __builtin_amdgcn_mfma_f32_16x16x16bf16_1k(pf, vf0, o0, 0, 0, 0);
    o1 = __builtin_amdgcn_mfma_f32_16x16x16bf16_1k(pf, vf1, o1, 0, 0, 0);
    o2 = __builtin_amdgcn_mfma_f32_16x16x16bf16_1k(pf, vf2, o2, 0, 0, 0);
    o3 = __builtin_amdgcn_mfma_f32_16x16x16bf16_1k(pf, vf3, o3, 0, 0, 0);
  }

  const float il0 = 1.f / __shfl(l_run, quad * 4 + 0);
  const float il1 = 1.f / __shfl(l_run, quad * 4 + 1);
  const float il2 = 1.f / __shfl(l_run, quad * 4 + 2);
  const float il3 = 1.f / __shfl(l_run, quad * 4 + 3);

  const int rowbase = qt * 64 + wave * 16 + quad * 4;
  const f4* oc[4] = {&o0, &o1, &o2, &o3};
  const float il[4] = {il0, il1, il2, il3};
  const size_t off0 = (size_t)rowbase * 1024 + col0 + hy * 64 + l15;
#pragma unroll
  for (int c = 0; c < 4; ++c)
#pragma unroll
    for (int r = 0; r < 4; ++r) {
      const float v = (*oc[c])[r] * il[r];
      if (BF16OUT)
        attH[off0 + (size_t)r * 1024 + c * 16] = f2bf(v);
      else
        attF[off0 + (size_t)r * 1024 + c * 16] = v;
    }
}

// ---------------------------------------------------------------------------
// Output projection (fast path): Out[m,n] = sum_k A[m,k]*Wo[n,k] + bo[n].
// A = att bf16 [4096][1024] in ws (GLDS staging); Wo fp32 (pack to bf16);
// Out fp32 to d_out. 128x128 tile, grid (8,32).
// ---------------------------------------------------------------------------
__global__ __launch_bounds__(256) void gemm_out_ws(
    const short* __restrict__ A, const float* __restrict__ W,
    const float* __restrict__ Bias, float* __restrict__ Out) {
  __shared__ short As[128 * 32];
  __shared__ short Bs[128 * 32];
  const int t = threadIdx.x;
  const int wave = t >> 6;
  const int lane = t & 63;
  const int l15 = lane & 15;
  const int quad = lane >> 4;
  const int m0 = blockIdx.y * 128;
  const int n0 = blockIdx.x * 128;
  const int wm = (wave & 1) * 64;
  const int wn = (wave >> 1) * 64;

  f4 acc[4][4];
#pragma unroll
  for (int i = 0; i < 4; ++i)
#pragma unroll
    for (int j = 0; j < 4; ++j) acc[i][j] = (f4){0.f, 0.f, 0.f, 0.f};

  const short* ag = A + (size_t)(m0 + (t >> 2)) * 1024 + (t & 3) * 8;
  const float* bg = W + (size_t)(n0 + (t >> 2)) * 1024 + (t & 3) * 8;
  short* al = As + wave * 512;  // wave-uniform GLDS base (+ lane*16B)

  for (int kt = 0; kt < 1024; kt += 32) {
    const sh8 b0 = pack8(*(const f4*)(bg + kt), *(const f4*)(bg + kt + 4));
    const sh8 b1 =
        pack8(*(const f4*)(bg + 65536 + kt), *(const f4*)(bg + 65536 + kt + 4));
    __syncthreads();  // prior iter's LDS reads complete
    GLDS16(ag + kt, al);
    GLDS16(ag + 65536 + kt, al + 2048);
    *(sh8*)(Bs + t * 8) = b0;
    *(sh8*)(Bs + 2048 + t * 8) = b1;
    __syncthreads();  // drains vmcnt (GLDS) + lgkm before use
    sh8 af[4], bf[4];
#pragma unroll
    for (int i = 0; i < 4; ++i) {
      af[i] = *(const sh8*)(As + (wm + i * 16 + l15) * 32 + quad * 8);
      bf[i] = *(const sh8*)(Bs + (wn + i * 16 + l15) * 32 + quad * 8);
    }
#pragma unroll
    for (int i = 0; i < 4; ++i)
#pragma unroll
      for (int j = 0; j < 4; ++j)
        acc[i][j] =
            __builtin_amdgcn_mfma_f32_16x16x32_bf16(af[i], bf[j], acc[i][j], 0, 0, 0);
  }

#pragma unroll
  for (int j = 0; j < 4; ++j) {
    const int n = n0 + wn + j * 16 + l15;
    const float bias = Bias[n];
#pragma unroll
    for (int i = 0; i < 4; ++i) {
#pragma unroll
      for (int r = 0; r < 4; ++r) {
        const int m = m0 + wm + i * 16 + quad * 4 + r;
        Out[(size_t)m * 1024 + n] = acc[i][j][r] + bias;
      }
    }
  }
}

// ---------------------------------------------------------------------------
// Fallback in-place output projection (round-6, known-passing).
// ---------------------------------------------------------------------------
__global__ __launch_bounds__(256) void outproj_inplace(
    float* __restrict__ AO, const float* __restrict__ W,
    const float* __restrict__ Bias) {
  __shared__ short attS[16 * 264];
  const int t = threadIdx.x;
  const int wave = t >> 6;
  const int lane = t & 63;
  const int l15 = lane & 15;
  const int quad = lane >> 4;
  const int m0 = blockIdx.x * 16;
  const int n0w = wave * 256;

  f4 acc[16];
#pragma unroll
  for (int i = 0; i < 16; ++i) acc[i] = (f4){0.f, 0.f, 0.f, 0.f};

  for (int kc = 0; kc < 4; ++kc) {
    __syncthreads();
#pragma unroll
    for (int i = 0; i < 2; ++i) {
      const int e = i * 2048 + t * 8;
      const int row = e >> 8;
      const int col = e & 255;
      const float* src = AO + (size_t)(m0 + row) * 1024 + kc * 256 + col;
      *(sh8*)(attS + row * 264 + col) =
          pack8(*(const f4*)src, *(const f4*)(src + 4));
    }
    __syncthreads();
    for (int ktl = 0; ktl < 256; ktl += 32) {
      const sh8 af = *(const sh8*)(attS + l15 * 264 + ktl + quad * 8);
      const int kt = kc * 256 + ktl;
#pragma unroll
      for (int nf = 0; nf < 16; ++nf) {
        const float* wp = W + (size_t)(n0w + nf * 16 + l15) * 1024 + kt + quad * 8;
        const sh8 bf = pack8(*(const f4*)wp, *(const f4*)(wp + 4));
        acc[nf] = __builtin_amdgcn_mfma_f32_16x16x32_bf16(af, bf, acc[nf], 0, 0, 0);
      }
    }
  }
  __syncthreads();

#pragma unroll
  for (int nf = 0; nf < 16; ++nf) {
    const int n = n0w + nf * 16 + l15;
    const float bias = Bias[n];
#pragma unroll
    for (int r = 0; r < 4; ++r) {
      const int m = m0 + quad * 4 + r;
      AO[(size_t)m * 1024 + n] = acc[nf][r] + bias;
    }
  }
}

// ---------------------------------------------------------------------------
extern "C" void kernel_launch(void* const* d_in, const int* in_sizes, int n_in,
                              void* d_out, int out_size, void* d_ws,
                              size_t ws_size, hipStream_t stream) {
  const float* x = (const float*)d_in[0];
  const float* wq = (const float*)d_in[1];
  const float* bq = (const float*)d_in[2];
  const float* wk = (const float*)d_in[3];
  const float* bk = (const float*)d_in[4];
  const float* wv = (const float*)d_in[5];
  const float* bv = (const float*)d_in[6];
  const float* wo = (const float*)d_in[7];
  const float* bo = (const float*)d_in[8];
  float* out = (float*)d_out;

  const size_t NEED_FAST = 21233664ULL;  // 12MB QKV + 8MB att + 256KB q2k2
  if (ws_size >= NEED_FAST) {
    short* Qp = (short*)d_ws;                    // 4MB  [h][n][64] bf16
    short* Kp = Qp + 2097152;                    // 4MB
    short* Vtp = Kp + 2097152;                   // 4MB  [h][64][n] bf16
    short* attAll = Vtp + 2097152;               // 8MB  [4096][1024] bf16
    float* q2 = (float*)(attAll + 4194304);      // 128KB
    float* k2 = q2 + 32768;                      // 128KB

    for (int b = 0; b < 2; ++b) {
      const float* xb = x + (size_t)b * 2097152;
      gemm_qkvp<<<dim3(24, 16), 256, 0, stream>>>(xb, wq, bq, wk, bk, wv, bv,
                                                  Qp, Kp, Vtp, 0, 8);
      sumsq<<<256, 256, 0, stream>>>(Qp, Kp, q2, k2, 32768);
      attn_t<1><<<dim3(32, 16), 256, 0, stream>>>(
          Qp, Kp, Vtp, q2, k2, nullptr, attAll + (size_t)b * 2097152, 0);
    }
    gemm_out_ws<<<dim3(8, 32), 256, 0, stream>>>(attAll, wo, bo, out);
  } else {
    // round-6 fallback: adaptive head-group size, att fp32 in d_out,
    // in-place out-projection.
    int G = 16;
    while (G > 2 && (size_t)G * 802816ULL > ws_size) G >>= 1;
    short* Qp = (short*)d_ws;
    short* Kp = Qp + (size_t)G * 131072;
    short* Vtp = Kp + (size_t)G * 131072;
    float* q2 = (float*)(Vtp + (size_t)G * 131072);
    float* k2 = q2 + (size_t)G * 2048;

    const int groups = 16 / G;
    for (int b = 0; b < 2; ++b) {
      const float* xb = x + (size_t)b * 2097152;
      float* attB = out + (size_t)b * 2097152;
      for (int g = 0; g < groups; ++g) {
        gemm_qkvp<<<dim3(3 * (G / 2), 16), 256, 0, stream>>>(
            xb, wq, bq, wk, bk, wv, bv, Qp, Kp, Vtp, g * G * 64, G / 2);
        sumsq<<<16 * G, 256, 0, stream>>>(Qp, Kp, q2, k2, G * 2048);
        attn_t<0><<<dim3(32, G), 256, 0, stream>>>(Qp, Kp, Vtp, q2, k2, attB,
                                                   nullptr, g * G * 64);
      }
    }
    outproj_inplace<<<256, 256, 0, stream>>>(out, wo, bo);
  }
}

// Round 8
// 573.857 us; speedup vs baseline: 1.2846x; 1.0025x over previous
//
#include <hip/hip_runtime.h>

// L2 self-attention. Inputs/outputs FP32; compute bf16 MFMA, fp32 accumulate.
// B=2 N=2048 D=1024 H=16 hd=64.
// attn v2: fixed softmax max = 0 (scores = -sqrt(d2) <= 0 always) -> no
// online-softmax state, no in-loop shuffles, independent iterations.
// Tier A (ws>=32.5MB): both batches' QKV resident, single attn launch
// grid (32,16,2) for 2x occupancy. Tier B (>=20.25MB): per-batch. Tier C:
// small-ws fallback (adaptive G, in-place outproj).

typedef __attribute__((ext_vector_type(8))) short sh8;   // 8 bf16 (4 VGPRs)
typedef __attribute__((ext_vector_type(4))) short sh4;   // 4 bf16 (2 VGPRs)
typedef __attribute__((ext_vector_type(4))) float f4;    // 4 fp32

__device__ __forceinline__ float bf2f(short s) {
  union { unsigned u; float f; } c;
  c.u = ((unsigned)(unsigned short)s) << 16;
  return c.f;
}
__device__ __forceinline__ short f2bf(float f) {
  union { float f; unsigned u; } c;
  c.f = f;
  unsigned u = c.u + 0x7FFFu + ((c.u >> 16) & 1u);  // RNE
  return (short)(u >> 16);
}
__device__ __forceinline__ sh8 pack8(f4 a, f4 b) {
  sh8 r;
  r[0] = f2bf(a[0]); r[1] = f2bf(a[1]); r[2] = f2bf(a[2]); r[3] = f2bf(a[3]);
  r[4] = f2bf(b[0]); r[5] = f2bf(b[1]); r[6] = f2bf(b[2]); r[7] = f2bf(b[3]);
  return r;
}

// async global->LDS, 16B per lane; LDS dest = wave-uniform base + lane*16
#define GLDS16(g, l)                                                      \
  __builtin_amdgcn_global_load_lds(                                       \
      (__attribute__((address_space(1))) void*)(void*)(g),                \
      (__attribute__((address_space(3))) void*)(void*)(l), 16, 0, 0)

// ---------------------------------------------------------------------------
// QKV projection for a group of heads. C[m,c] = sum_k X[m,k]*W[c,k]+bias.
// blockIdx.x in [0, 3*nblkP): which = /nblkP, col-block = %nblkP (128 cols).
// Qp,Kp stored bf16 [hl][n][64]; Vtp bf16 transposed [hl][64][n].
// ---------------------------------------------------------------------------
__global__ __launch_bounds__(256) void gemm_qkvp(
    const float* __restrict__ X,   // batch rows: 2048 x 1024 fp32
    const float* __restrict__ Wq, const float* __restrict__ Bq,
    const float* __restrict__ Wk, const float* __restrict__ Bk,
    const float* __restrict__ Wv, const float* __restrict__ Bv,
    short* __restrict__ Qp, short* __restrict__ Kp, short* __restrict__ Vtp,
    int w0, int nblkP) {
  __shared__ short As[128 * 32];
  __shared__ short Bs[128 * 32];
  const int t = threadIdx.x;
  const int wave = t >> 6;
  const int lane = t & 63;
  const int l15 = lane & 15;
  const int quad = lane >> 4;
  const int m0 = blockIdx.y * 128;
  const int which = blockIdx.x / nblkP;            // 0=Q 1=K 2=V
  const int nblk = blockIdx.x % nblkP;
  const int n0l = nblk * 128;
  const int wrow0 = w0 + n0l;
  const float* W = (which == 0) ? Wq : ((which == 1) ? Wk : Wv);
  const float* Bias = (which == 0) ? Bq : ((which == 1) ? Bk : Bv);
  const int wm = (wave & 1) * 64;
  const int wn = (wave >> 1) * 64;

  f4 acc[4][4];
#pragma unroll
  for (int i = 0; i < 4; ++i)
#pragma unroll
    for (int j = 0; j < 4; ++j) acc[i][j] = (f4){0.f, 0.f, 0.f, 0.f};

  const float* ag = X + (size_t)(m0 + (t >> 2)) * 1024 + (t & 3) * 8;
  const float* bg = W + (size_t)(wrow0 + (t >> 2)) * 1024 + (t & 3) * 8;

  for (int kt = 0; kt < 1024; kt += 32) {
    const sh8 a0 = pack8(*(const f4*)(ag + kt), *(const f4*)(ag + kt + 4));
    const sh8 a1 =
        pack8(*(const f4*)(ag + 65536 + kt), *(const f4*)(ag + 65536 + kt + 4));
    const sh8 b0 = pack8(*(const f4*)(bg + kt), *(const f4*)(bg + kt + 4));
    const sh8 b1 =
        pack8(*(const f4*)(bg + 65536 + kt), *(const f4*)(bg + 65536 + kt + 4));
    __syncthreads();
    *(sh8*)(As + t * 8) = a0;
    *(sh8*)(As + 2048 + t * 8) = a1;
    *(sh8*)(Bs + t * 8) = b0;
    *(sh8*)(Bs + 2048 + t * 8) = b1;
    __syncthreads();
    sh8 af[4], bf[4];
#pragma unroll
    for (int i = 0; i < 4; ++i) {
      af[i] = *(const sh8*)(As + (wm + i * 16 + l15) * 32 + quad * 8);
      bf[i] = *(const sh8*)(Bs + (wn + i * 16 + l15) * 32 + quad * 8);
    }
#pragma unroll
    for (int i = 0; i < 4; ++i)
#pragma unroll
      for (int j = 0; j < 4; ++j)
        acc[i][j] =
            __builtin_amdgcn_mfma_f32_16x16x32_bf16(af[i], bf[j], acc[i][j], 0, 0, 0);
  }

#pragma unroll
  for (int j = 0; j < 4; ++j) {
    const int ngl = n0l + wn + j * 16 + l15;
    const float bias = Bias[w0 + ngl];
    const int hl = ngl >> 6;
    const int d = ngl & 63;
#pragma unroll
    for (int i = 0; i < 4; ++i) {
#pragma unroll
      for (int r = 0; r < 4; ++r) {
        const int m = m0 + wm + i * 16 + quad * 4 + r;
        const short o = f2bf(acc[i][j][r] + bias);
        if (which == 0)
          Qp[((size_t)hl * 2048 + m) * 64 + d] = o;
        else if (which == 1)
          Kp[((size_t)hl * 2048 + m) * 64 + d] = o;
        else
          Vtp[((size_t)hl * 64 + d) * 2048 + m] = o;
      }
    }
  }
}

// ---------------------------------------------------------------------------
// Sums of squares of bf16-rounded Q and K rows. R rows per tensor.
// ---------------------------------------------------------------------------
__global__ __launch_bounds__(256) void sumsq(const short* __restrict__ Qp,
                                             const short* __restrict__ Kp,
                                             float* __restrict__ q2a,
                                             float* __restrict__ k2a, int R) {
  const int tid = blockIdx.x * 256 + threadIdx.x;
  const bool isQ = tid < R;
  const int r = isQ ? tid : tid - R;
  const short* p = (isQ ? Qp : Kp) + (size_t)r * 64;
  float s = 0.f;
#pragma unroll
  for (int i = 0; i < 8; ++i) {
    sh8 v = *(const sh8*)(p + i * 8);
#pragma unroll
    for (int j = 0; j < 8; ++j) {
      float f = bf2f(v[j]);
      s = fmaf(f, f, s);
    }
  }
  (isQ ? q2a : k2a)[r] = s;
}

// ---------------------------------------------------------------------------
// Flash attention v2: fixed softmax max = 0 (scores <= 0 always), so no
// running max / rescale / in-loop shuffles; iterations independent.
// Block = 4 waves; wave owns 16 queries; 16-key tiles, unroll x2.
// S^T = MFMA(A=K, B=Q): C row=key(quad*4+r), col=query(l15) == A-operand
// layout of P for mfma 16x16x16 PV. O C-layout: row=query, col=vdim chunk.
// blockIdx.z = batch (head slot hb = z*gridDim.y + y; att row += z*2048).
// ---------------------------------------------------------------------------
template <int BF16OUT>
__global__ __launch_bounds__(256) void attn_t(
    const short* __restrict__ Qp, const short* __restrict__ Kp,
    const short* __restrict__ Vtp, const float* __restrict__ q2a,
    const float* __restrict__ k2a, float* __restrict__ attF,
    short* __restrict__ attH, int col0) {
  const int t = threadIdx.x;
  const int wave = t >> 6;
  const int lane = t & 63;
  const int l15 = lane & 15;
  const int quad = lane >> 4;
  const int hy = blockIdx.y;
  const int qt = blockIdx.x;
  const int bz = blockIdx.z;
  const size_t hb = (size_t)bz * gridDim.y + hy;   // head slot
  const size_t base = hb * 2048;
  const int qrow = qt * 64 + wave * 16 + l15;

  const short* qp = Qp + (base + qrow) * 64 + quad * 8;
  const sh8 qf0 = *(const sh8*)qp;
  const sh8 qf1 = *(const sh8*)(qp + 32);
  const float q2 = q2a[base + qrow];

  float l_run = 0.f;
  f4 o0 = (f4){0.f, 0.f, 0.f, 0.f}, o1 = o0, o2 = o0, o3 = o0;

  const short* kbase = Kp + (base + l15) * 64 + quad * 8;
  const float* k2p = k2a + base + quad * 4;
  const short* vbase = Vtp + (hb * 64 + l15) * 2048 + quad * 4;

  for (int j0 = 0; j0 < 2048; j0 += 32) {
#pragma unroll
    for (int u = 0; u < 2; ++u) {
      const int j = j0 + u * 16;
      const sh8 kf0 = *(const sh8*)(kbase + (size_t)j * 64);
      const sh8 kf1 = *(const sh8*)(kbase + (size_t)j * 64 + 32);
      f4 st = (f4){0.f, 0.f, 0.f, 0.f};
      st = __builtin_amdgcn_mfma_f32_16x16x32_bf16(kf0, qf0, st, 0, 0, 0);
      st = __builtin_amdgcn_mfma_f32_16x16x32_bf16(kf1, qf1, st, 0, 0, 0);
      const f4 k2v = *(const f4*)(k2p + j);
      float p[4];
#pragma unroll
      for (int r = 0; r < 4; ++r) {
        const float d2 = fmaxf(fmaf(-2.f, st[r], q2 + k2v[r]), 1e-12f);
        p[r] = __expf(-sqrtf(d2));   // exp(score), score <= 0: never overflows
      }
      l_run += (p[0] + p[1]) + (p[2] + p[3]);
      sh4 pf;
#pragma unroll
      for (int r = 0; r < 4; ++r) pf[r] = f2bf(p[r]);
      const sh4 vf0 = *(const sh4*)(vbase + j);
      const sh4 vf1 = *(const sh4*)(vbase + 16 * 2048 + j);
      const sh4 vf2 = *(const sh4*)(vbase + 32 * 2048 + j);
      const sh4 vf3 = *(const sh4*)(vbase + 48 * 2048 + j);
      o0 = __builtin_amdgcn_mfma_f32_16x16x16bf16_1k(pf, vf0, o0, 0, 0, 0);
      o1 = __builtin_amdgcn_mfma_f32_16x16x16bf16_1k(pf, vf1, o1, 0, 0, 0);
      o2 = __builtin_amdgcn_mfma_f32_16x16x16bf16_1k(pf, vf2, o2, 0, 0, 0);
      o3 = __builtin_amdgcn_mfma_f32_16x16x16bf16_1k(pf, vf3, o3, 0, 0, 0);
    }
  }

  // l for query l15: reduce partials over quads (keys were split by quad)
  l_run += __shfl_xor(l_run, 16);
  l_run += __shfl_xor(l_run, 32);
  // inverse-l for O rows (query = quad*4+r): lane i<16 holds l for query i
  const float il0 = 1.f / __shfl(l_run, quad * 4 + 0);
  const float il1 = 1.f / __shfl(l_run, quad * 4 + 1);
  const float il2 = 1.f / __shfl(l_run, quad * 4 + 2);
  const float il3 = 1.f / __shfl(l_run, quad * 4 + 3);

  const int rowbase = qt * 64 + wave * 16 + quad * 4;
  const f4* oc[4] = {&o0, &o1, &o2, &o3};
  const float il[4] = {il0, il1, il2, il3};
  const size_t off0 =
      ((size_t)bz * 2048 + rowbase) * 1024 + col0 + hy * 64 + l15;
#pragma unroll
  for (int c = 0; c < 4; ++c)
#pragma unroll
    for (int r = 0; r < 4; ++r) {
      const float v = (*oc[c])[r] * il[r];
      if (BF16OUT)
        attH[off0 + (size_t)r * 1024 + c * 16] = f2bf(v);
      else
        attF[off0 + (size_t)r * 1024 + c * 16] = v;
    }
}

// ---------------------------------------------------------------------------
// Output projection: Out[m,n] = sum_k A[m,k]*Wo[n,k] + bo[n].
// A = att bf16 [4096][1024] in ws (GLDS staging); Wo fp32 (pack to bf16).
// ---------------------------------------------------------------------------
__global__ __launch_bounds__(256) void gemm_out_ws(
    const short* __restrict__ A, const float* __restrict__ W,
    const float* __restrict__ Bias, float* __restrict__ Out) {
  __shared__ short As[128 * 32];
  __shared__ short Bs[128 * 32];
  const int t = threadIdx.x;
  const int wave = t >> 6;
  const int lane = t & 63;
  const int l15 = lane & 15;
  const int quad = lane >> 4;
  const int m0 = blockIdx.y * 128;
  const int n0 = blockIdx.x * 128;
  const int wm = (wave & 1) * 64;
  const int wn = (wave >> 1) * 64;

  f4 acc[4][4];
#pragma unroll
  for (int i = 0; i < 4; ++i)
#pragma unroll
    for (int j = 0; j < 4; ++j) acc[i][j] = (f4){0.f, 0.f, 0.f, 0.f};

  const short* ag = A + (size_t)(m0 + (t >> 2)) * 1024 + (t & 3) * 8;
  const float* bg = W + (size_t)(n0 + (t >> 2)) * 1024 + (t & 3) * 8;
  short* al = As + wave * 512;

  for (int kt = 0; kt < 1024; kt += 32) {
    const sh8 b0 = pack8(*(const f4*)(bg + kt), *(const f4*)(bg + kt + 4));
    const sh8 b1 =
        pack8(*(const f4*)(bg + 65536 + kt), *(const f4*)(bg + 65536 + kt + 4));
    __syncthreads();
    GLDS16(ag + kt, al);
    GLDS16(ag + 65536 + kt, al + 2048);
    *(sh8*)(Bs + t * 8) = b0;
    *(sh8*)(Bs + 2048 + t * 8) = b1;
    __syncthreads();
    sh8 af[4], bf[4];
#pragma unroll
    for (int i = 0; i < 4; ++i) {
      af[i] = *(const sh8*)(As + (wm + i * 16 + l15) * 32 + quad * 8);
      bf[i] = *(const sh8*)(Bs + (wn + i * 16 + l15) * 32 + quad * 8);
    }
#pragma unroll
    for (int i = 0; i < 4; ++i)
#pragma unroll
      for (int j = 0; j < 4; ++j)
        acc[i][j] =
            __builtin_amdgcn_mfma_f32_16x16x32_bf16(af[i], bf[j], acc[i][j], 0, 0, 0);
  }

#pragma unroll
  for (int j = 0; j < 4; ++j) {
    const int n = n0 + wn + j * 16 + l15;
    const float bias = Bias[n];
#pragma unroll
    for (int i = 0; i < 4; ++i) {
#pragma unroll
      for (int r = 0; r < 4; ++r) {
        const int m = m0 + wm + i * 16 + quad * 4 + r;
        Out[(size_t)m * 1024 + n] = acc[i][j][r] + bias;
      }
    }
  }
}

// ---------------------------------------------------------------------------
// Fallback in-place output projection (small ws).
// ---------------------------------------------------------------------------
__global__ __launch_bounds__(256) void outproj_inplace(
    float* __restrict__ AO, const float* __restrict__ W,
    const float* __restrict__ Bias) {
  __shared__ short attS[16 * 264];
  const int t = threadIdx.x;
  const int wave = t >> 6;
  const int lane = t & 63;
  const int l15 = lane & 15;
  const int quad = lane >> 4;
  const int m0 = blockIdx.x * 16;
  const int n0w = wave * 256;

  f4 acc[16];
#pragma unroll
  for (int i = 0; i < 16; ++i) acc[i] = (f4){0.f, 0.f, 0.f, 0.f};

  for (int kc = 0; kc < 4; ++kc) {
    __syncthreads();
#pragma unroll
    for (int i = 0; i < 2; ++i) {
      const int e = i * 2048 + t * 8;
      const int row = e >> 8;
      const int col = e & 255;
      const float* src = AO + (size_t)(m0 + row) * 1024 + kc * 256 + col;
      *(sh8*)(attS + row * 264 + col) =
          pack8(*(const f4*)src, *(const f4*)(src + 4));
    }
    __syncthreads();
    for (int ktl = 0; ktl < 256; ktl += 32) {
      const sh8 af = *(const sh8*)(attS + l15 * 264 + ktl + quad * 8);
      const int kt = kc * 256 + ktl;
#pragma unroll
      for (int nf = 0; nf < 16; ++nf) {
        const float* wp = W + (size_t)(n0w + nf * 16 + l15) * 1024 + kt + quad * 8;
        const sh8 bf = pack8(*(const f4*)wp, *(const f4*)(wp + 4));
        acc[nf] = __builtin_amdgcn_mfma_f32_16x16x32_bf16(af, bf, acc[nf], 0, 0, 0);
      }
    }
  }
  __syncthreads();

#pragma unroll
  for (int nf = 0; nf < 16; ++nf) {
    const int n = n0w + nf * 16 + l15;
    const float bias = Bias[n];
#pragma unroll
    for (int r = 0; r < 4; ++r) {
      const int m = m0 + quad * 4 + r;
      AO[(size_t)m * 1024 + n] = acc[nf][r] + bias;
    }
  }
}

// ---------------------------------------------------------------------------
extern "C" void kernel_launch(void* const* d_in, const int* in_sizes, int n_in,
                              void* d_out, int out_size, void* d_ws,
                              size_t ws_size, hipStream_t stream) {
  const float* x = (const float*)d_in[0];
  const float* wq = (const float*)d_in[1];
  const float* bq = (const float*)d_in[2];
  const float* wk = (const float*)d_in[3];
  const float* bk = (const float*)d_in[4];
  const float* wv = (const float*)d_in[5];
  const float* bv = (const float*)d_in[6];
  const float* wo = (const float*)d_in[7];
  const float* bo = (const float*)d_in[8];
  float* out = (float*)d_out;

  const size_t NEED_A = 34078720ULL;  // 24MB QKV(2b) + 8MB att + 512KB q2k2
  const size_t NEED_B = 21233664ULL;  // 12MB QKV(1b) + 8MB att + 256KB q2k2

  if (ws_size >= NEED_A) {
    // Tier A: both batches resident; single high-occupancy attn launch.
    short* Qp = (short*)d_ws;                 // [b*16+h][2048][64] bf16, 8MB
    short* Kp = Qp + 4194304;                 // 8MB
    short* Vtp = Kp + 4194304;                // [b*16+h][64][2048] bf16, 8MB
    short* attAll = Vtp + 4194304;            // [4096][1024] bf16, 8MB
    float* q2 = (float*)(attAll + 4194304);   // 256KB  [b*16+h][2048]
    float* k2 = q2 + 65536;                   // 256KB

    for (int b = 0; b < 2; ++b) {
      gemm_qkvp<<<dim3(24, 16), 256, 0, stream>>>(
          x + (size_t)b * 2097152, wq, bq, wk, bk, wv, bv,
          Qp + (size_t)b * 2097152, Kp + (size_t)b * 2097152,
          Vtp + (size_t)b * 2097152, 0, 8);
    }
    sumsq<<<512, 256, 0, stream>>>(Qp, Kp, q2, k2, 65536);
    attn_t<1><<<dim3(32, 16, 2), 256, 0, stream>>>(Qp, Kp, Vtp, q2, k2,
                                                   nullptr, attAll, 0);
    gemm_out_ws<<<dim3(8, 32), 256, 0, stream>>>(attAll, wo, bo, out);
  } else if (ws_size >= NEED_B) {
    // Tier B: per-batch.
    short* Qp = (short*)d_ws;
    short* Kp = Qp + 2097152;
    short* Vtp = Kp + 2097152;
    short* attAll = Vtp + 2097152;            // [4096][1024] bf16, 8MB
    float* q2 = (float*)(attAll + 4194304);
    float* k2 = q2 + 32768;

    for (int b = 0; b < 2; ++b) {
      const float* xb = x + (size_t)b * 2097152;
      gemm_qkvp<<<dim3(24, 16), 256, 0, stream>>>(xb, wq, bq, wk, bk, wv, bv,
                                                  Qp, Kp, Vtp, 0, 8);
      sumsq<<<256, 256, 0, stream>>>(Qp, Kp, q2, k2, 32768);
      attn_t<1><<<dim3(32, 16, 1), 256, 0, stream>>>(
          Qp, Kp, Vtp, q2, k2, nullptr, attAll + (size_t)b * 2097152, 0);
    }
    gemm_out_ws<<<dim3(8, 32), 256, 0, stream>>>(attAll, wo, bo, out);
  } else {
    // Tier C: small-ws fallback (att fp32 in d_out, in-place outproj).
    int G = 16;
    while (G > 2 && (size_t)G * 802816ULL > ws_size) G >>= 1;
    short* Qp = (short*)d_ws;
    short* Kp = Qp + (size_t)G * 131072;
    short* Vtp = Kp + (size_t)G * 131072;
    float* q2 = (float*)(Vtp + (size_t)G * 131072);
    float* k2 = q2 + (size_t)G * 2048;

    const int groups = 16 / G;
    for (int b = 0; b < 2; ++b) {
      const float* xb = x + (size_t)b * 2097152;
      float* attB = out + (size_t)b * 2097152;
      for (int g = 0; g < groups; ++g) {
        gemm_qkvp<<<dim3(3 * (G / 2), 16), 256, 0, stream>>>(
            xb, wq, bq, wk, bk, wv, bv, Qp, Kp, Vtp, g * G * 64, G / 2);
        sumsq<<<16 * G, 256, 0, stream>>>(Qp, Kp, q2, k2, G * 2048);
        attn_t<0><<<dim3(32, G, 1), 256, 0, stream>>>(Qp, Kp, Vtp, q2, k2,
                                                      attB, nullptr, g * G * 64);
      }
    }
    outproj_inplace<<<256, 256, 0, stream>>>(out, wo, bo);
  }
}

// Round 9
// 315.287 us; speedup vs baseline: 2.3381x; 1.8201x over previous
//
#include <hip/hip_runtime.h>

// L2 self-attention. Inputs/outputs FP32; compute bf16 MFMA, fp32 accumulate.
// B=2 N=2048 D=1024 H=16 hd=64.
// attn3: LDS-staged flash attention. 8-wave blocks stage K(128x64) and
// Vt(64x128) tiles to LDS once (padded strides 72/136 -> conflict-free reads),
// all 8 waves consume them. Fixed softmax max = 0 (scores <= 0 always).
// Tier A2 (ws>=48.5MB): X/W pre-converted to bf16 -> all GEMMs pure GLDS16.
// Tier A (>=32.5MB): fp32-staging GEMMs + attn3. Tier C: small-ws fallback.

typedef __attribute__((ext_vector_type(8))) short sh8;   // 8 bf16 (4 VGPRs)
typedef __attribute__((ext_vector_type(4))) short sh4;   // 4 bf16 (2 VGPRs)
typedef __attribute__((ext_vector_type(4))) float f4;    // 4 fp32

__device__ __forceinline__ float bf2f(short s) {
  union { unsigned u; float f; } c;
  c.u = ((unsigned)(unsigned short)s) << 16;
  return c.f;
}
__device__ __forceinline__ short f2bf(float f) {
  union { float f; unsigned u; } c;
  c.f = f;
  unsigned u = c.u + 0x7FFFu + ((c.u >> 16) & 1u);  // RNE
  return (short)(u >> 16);
}
__device__ __forceinline__ sh8 pack8(f4 a, f4 b) {
  sh8 r;
  r[0] = f2bf(a[0]); r[1] = f2bf(a[1]); r[2] = f2bf(a[2]); r[3] = f2bf(a[3]);
  r[4] = f2bf(b[0]); r[5] = f2bf(b[1]); r[6] = f2bf(b[2]); r[7] = f2bf(b[3]);
  return r;
}

// async global->LDS, 16B per lane; LDS dest = wave-uniform base + lane*16
#define GLDS16(g, l)                                                      \
  __builtin_amdgcn_global_load_lds(                                       \
      (__attribute__((address_space(1))) void*)(void*)(g),                \
      (__attribute__((address_space(3))) void*)(void*)(l), 16, 0, 0)

// ---------------------------------------------------------------------------
// fp32 -> bf16 elementwise (n multiple of 8)
// ---------------------------------------------------------------------------
__global__ __launch_bounds__(256) void cvt_bf16(const float* __restrict__ src,
                                                short* __restrict__ dst, int n) {
  const int i = (blockIdx.x * 256 + threadIdx.x) * 8;
  if (i < n)
    *(sh8*)(dst + i) = pack8(*(const f4*)(src + i), *(const f4*)(src + i + 4));
}

// ---------------------------------------------------------------------------
// QKV projection, fp32 inputs (Tier A): pack8 staging.
// ---------------------------------------------------------------------------
__global__ __launch_bounds__(256) void gemm_qkvp(
    const float* __restrict__ X, const float* __restrict__ Wq,
    const float* __restrict__ Bq, const float* __restrict__ Wk,
    const float* __restrict__ Bk, const float* __restrict__ Wv,
    const float* __restrict__ Bv, short* __restrict__ Qp,
    short* __restrict__ Kp, short* __restrict__ Vtp, int w0, int nblkP) {
  __shared__ short As[128 * 32];
  __shared__ short Bs[128 * 32];
  const int t = threadIdx.x;
  const int wave = t >> 6;
  const int lane = t & 63;
  const int l15 = lane & 15;
  const int quad = lane >> 4;
  const int m0 = blockIdx.y * 128;
  const int which = blockIdx.x / nblkP;
  const int n0l = (blockIdx.x % nblkP) * 128;
  const int wrow0 = w0 + n0l;
  const float* W = (which == 0) ? Wq : ((which == 1) ? Wk : Wv);
  const float* Bias = (which == 0) ? Bq : ((which == 1) ? Bk : Bv);
  const int wm = (wave & 1) * 64;
  const int wn = (wave >> 1) * 64;

  f4 acc[4][4];
#pragma unroll
  for (int i = 0; i < 4; ++i)
#pragma unroll
    for (int j = 0; j < 4; ++j) acc[i][j] = (f4){0.f, 0.f, 0.f, 0.f};

  const float* ag = X + (size_t)(m0 + (t >> 2)) * 1024 + (t & 3) * 8;
  const float* bg = W + (size_t)(wrow0 + (t >> 2)) * 1024 + (t & 3) * 8;

  for (int kt = 0; kt < 1024; kt += 32) {
    const sh8 a0 = pack8(*(const f4*)(ag + kt), *(const f4*)(ag + kt + 4));
    const sh8 a1 =
        pack8(*(const f4*)(ag + 65536 + kt), *(const f4*)(ag + 65536 + kt + 4));
    const sh8 b0 = pack8(*(const f4*)(bg + kt), *(const f4*)(bg + kt + 4));
    const sh8 b1 =
        pack8(*(const f4*)(bg + 65536 + kt), *(const f4*)(bg + 65536 + kt + 4));
    __syncthreads();
    *(sh8*)(As + t * 8) = a0;
    *(sh8*)(As + 2048 + t * 8) = a1;
    *(sh8*)(Bs + t * 8) = b0;
    *(sh8*)(Bs + 2048 + t * 8) = b1;
    __syncthreads();
    sh8 af[4], bf[4];
#pragma unroll
    for (int i = 0; i < 4; ++i) {
      af[i] = *(const sh8*)(As + (wm + i * 16 + l15) * 32 + quad * 8);
      bf[i] = *(const sh8*)(Bs + (wn + i * 16 + l15) * 32 + quad * 8);
    }
#pragma unroll
    for (int i = 0; i < 4; ++i)
#pragma unroll
      for (int j = 0; j < 4; ++j)
        acc[i][j] =
            __builtin_amdgcn_mfma_f32_16x16x32_bf16(af[i], bf[j], acc[i][j], 0, 0, 0);
  }

#pragma unroll
  for (int j = 0; j < 4; ++j) {
    const int ngl = n0l + wn + j * 16 + l15;
    const float bias = Bias[w0 + ngl];
    const int hl = ngl >> 6;
    const int d = ngl & 63;
#pragma unroll
    for (int i = 0; i < 4; ++i) {
#pragma unroll
      for (int r = 0; r < 4; ++r) {
        const int m = m0 + wm + i * 16 + quad * 4 + r;
        const short o = f2bf(acc[i][j][r] + bias);
        if (which == 0)
          Qp[((size_t)hl * 2048 + m) * 64 + d] = o;
        else if (which == 1)
          Kp[((size_t)hl * 2048 + m) * 64 + d] = o;
        else
          Vtp[((size_t)hl * 64 + d) * 2048 + m] = o;
      }
    }
  }
}

// ---------------------------------------------------------------------------
// QKV projection, bf16 pre-converted inputs (Tier A2): GLDS16 both operands.
// ---------------------------------------------------------------------------
__global__ __launch_bounds__(256) void gemm_qkv_bf(
    const short* __restrict__ X, const short* __restrict__ Wq,
    const float* __restrict__ Bq, const short* __restrict__ Wk,
    const float* __restrict__ Bk, const short* __restrict__ Wv,
    const float* __restrict__ Bv, short* __restrict__ Qp,
    short* __restrict__ Kp, short* __restrict__ Vtp) {
  __shared__ short As[128 * 32];
  __shared__ short Bs[128 * 32];
  const int t = threadIdx.x;
  const int wave = t >> 6;
  const int lane = t & 63;
  const int l15 = lane & 15;
  const int quad = lane >> 4;
  const int m0 = blockIdx.y * 128;
  const int which = blockIdx.x >> 3;     // 0=Q 1=K 2=V
  const int n0l = (blockIdx.x & 7) * 128;
  const short* W = (which == 0) ? Wq : ((which == 1) ? Wk : Wv);
  const float* Bias = (which == 0) ? Bq : ((which == 1) ? Bk : Bv);
  const int wm = (wave & 1) * 64;
  const int wn = (wave >> 1) * 64;

  f4 acc[4][4];
#pragma unroll
  for (int i = 0; i < 4; ++i)
#pragma unroll
    for (int j = 0; j < 4; ++j) acc[i][j] = (f4){0.f, 0.f, 0.f, 0.f};

  const short* ag = X + (size_t)(m0 + (t >> 2)) * 1024 + (t & 3) * 8;
  const short* bg = W + (size_t)(n0l + (t >> 2)) * 1024 + (t & 3) * 8;
  short* al = As + wave * 512;
  short* bl = Bs + wave * 512;

  for (int kt = 0; kt < 1024; kt += 32) {
    __syncthreads();
    GLDS16(ag + kt, al);
    GLDS16(ag + 65536 + kt, al + 2048);
    GLDS16(bg + kt, bl);
    GLDS16(bg + 65536 + kt, bl + 2048);
    __syncthreads();
    sh8 af[4], bf[4];
#pragma unroll
    for (int i = 0; i < 4; ++i) {
      af[i] = *(const sh8*)(As + (wm + i * 16 + l15) * 32 + quad * 8);
      bf[i] = *(const sh8*)(Bs + (wn + i * 16 + l15) * 32 + quad * 8);
    }
#pragma unroll
    for (int i = 0; i < 4; ++i)
#pragma unroll
      for (int j = 0; j < 4; ++j)
        acc[i][j] =
            __builtin_amdgcn_mfma_f32_16x16x32_bf16(af[i], bf[j], acc[i][j], 0, 0, 0);
  }

#pragma unroll
  for (int j = 0; j < 4; ++j) {
    const int ngl = n0l + wn + j * 16 + l15;
    const float bias = Bias[ngl];
    const int hl = ngl >> 6;
    const int d = ngl & 63;
#pragma unroll
    for (int i = 0; i < 4; ++i) {
#pragma unroll
      for (int r = 0; r < 4; ++r) {
        const int m = m0 + wm + i * 16 + quad * 4 + r;
        const short o = f2bf(acc[i][j][r] + bias);
        if (which == 0)
          Qp[((size_t)hl * 2048 + m) * 64 + d] = o;
        else if (which == 1)
          Kp[((size_t)hl * 2048 + m) * 64 + d] = o;
        else
          Vtp[((size_t)hl * 64 + d) * 2048 + m] = o;
      }
    }
  }
}

// ---------------------------------------------------------------------------
// Sums of squares of bf16-rounded Q and K rows. R rows per tensor.
// ---------------------------------------------------------------------------
__global__ __launch_bounds__(256) void sumsq(const short* __restrict__ Qp,
                                             const short* __restrict__ Kp,
                                             float* __restrict__ q2a,
                                             float* __restrict__ k2a, int R) {
  const int tid = blockIdx.x * 256 + threadIdx.x;
  const bool isQ = tid < R;
  const int r = isQ ? tid : tid - R;
  const short* p = (isQ ? Qp : Kp) + (size_t)r * 64;
  float s = 0.f;
#pragma unroll
  for (int i = 0; i < 8; ++i) {
    sh8 v = *(const sh8*)(p + i * 8);
#pragma unroll
    for (int j = 0; j < 8; ++j) {
      float f = bf2f(v[j]);
      s = fmaf(f, f, s);
    }
  }
  (isQ ? q2a : k2a)[r] = s;
}

// ---------------------------------------------------------------------------
// attn3: LDS-staged flash attention, fixed max=0. Block = 8 waves = 128
// queries; K-tiles of 128 staged to LDS (Ks stride 72, Vs stride 136 ->
// conflict-minimal ds reads). Wave owns 16 queries.
// S^T = MFMA(A=Kfrag, B=Qfrag): C row=key(quad*4+r), col=query(l15) ==
// A-layout of P for 16x16x16 PV. O C-layout: row=query, col=vdim chunk.
// ---------------------------------------------------------------------------
__global__ __launch_bounds__(512, 4) void attn3(
    const short* __restrict__ Qp, const short* __restrict__ Kp,
    const short* __restrict__ Vtp, const float* __restrict__ q2a,
    const float* __restrict__ k2a, short* __restrict__ attH) {
  __shared__ short Ks[128 * 72];   // [key][64 dims + 8 pad] = 18 KB
  __shared__ short Vs[64 * 136];   // [dim][128 keys + 8 pad] = 17 KB
  const int t = threadIdx.x;
  const int wave = t >> 6;
  const int lane = t & 63;
  const int l15 = lane & 15;
  const int quad = lane >> 4;
  const int hy = blockIdx.y;
  const int qt = blockIdx.x;       // 0..15 (128 queries each)
  const int bz = blockIdx.z;
  const size_t hb = (size_t)bz * gridDim.y + hy;
  const size_t base = hb * 2048;
  const int qrow = qt * 128 + wave * 16 + l15;

  const short* qp = Qp + (base + qrow) * 64 + quad * 8;
  const sh8 qf0 = *(const sh8*)qp;
  const sh8 qf1 = *(const sh8*)(qp + 32);
  const float q2 = q2a[base + qrow];

  float l_run = 0.f;
  f4 o0 = (f4){0.f, 0.f, 0.f, 0.f}, o1 = o0, o2 = o0, o3 = o0;

  const float* k2p = k2a + base + quad * 4;

  for (int k0 = 0; k0 < 2048; k0 += 128) {
    // --- stage K (128x64) and Vt (64x128) tiles, coalesced sh8 loads ---
    sh8 kv0, kv1, vv0, vv1;
    {
      const short* kg = Kp + (base + k0 + (t >> 3)) * 64 + (t & 7) * 8;
      kv0 = *(const sh8*)kg;
      kv1 = *(const sh8*)(kg + 64 * 64);
      const short* vg =
          Vtp + (hb * 64 + (t >> 4)) * 2048 + k0 + (t & 15) * 8;
      vv0 = *(const sh8*)vg;
      vv1 = *(const sh8*)(vg + 32 * 2048);
    }
    __syncthreads();  // prior sub-tile reads complete
    *(sh8*)(Ks + (t >> 3) * 72 + (t & 7) * 8) = kv0;
    *(sh8*)(Ks + (64 + (t >> 3)) * 72 + (t & 7) * 8) = kv1;
    *(sh8*)(Vs + (t >> 4) * 136 + (t & 15) * 8) = vv0;
    *(sh8*)(Vs + (32 + (t >> 4)) * 136 + (t & 15) * 8) = vv1;
    __syncthreads();

    // --- 8 sub-tiles of 16 keys ---
#pragma unroll
    for (int sub = 0; sub < 8; ++sub) {
      const int j = sub * 16;
      const sh8 kf0 = *(const sh8*)(Ks + (j + l15) * 72 + quad * 8);
      const sh8 kf1 = *(const sh8*)(Ks + (j + l15) * 72 + 32 + quad * 8);
      f4 st = (f4){0.f, 0.f, 0.f, 0.f};
      st = __builtin_amdgcn_mfma_f32_16x16x32_bf16(kf0, qf0, st, 0, 0, 0);
      st = __builtin_amdgcn_mfma_f32_16x16x32_bf16(kf1, qf1, st, 0, 0, 0);
      const f4 k2v = *(const f4*)(k2p + k0 + j);
      float p[4];
#pragma unroll
      for (int r = 0; r < 4; ++r) {
        const float d2 = fmaxf(fmaf(-2.f, st[r], q2 + k2v[r]), 1e-12f);
        p[r] = __expf(-sqrtf(d2));  // score <= 0: never overflows
      }
      l_run += (p[0] + p[1]) + (p[2] + p[3]);
      sh4 pf;
#pragma unroll
      for (int r = 0; r < 4; ++r) pf[r] = f2bf(p[r]);
      const sh4 vf0 = *(const sh4*)(Vs + l15 * 136 + j + quad * 4);
      const sh4 vf1 = *(const sh4*)(Vs + (l15 + 16) * 136 + j + quad * 4);
      const sh4 vf2 = *(const sh4*)(Vs + (l15 + 32) * 136 + j + quad * 4);
      const sh4 vf3 = *(const sh4*)(Vs + (l15 + 48) * 136 + j + quad * 4);
      o0 = __builtin_amdgcn_mfma_f32_16x16x16bf16_1k(pf, vf0, o0, 0, 0, 0);
      o1 = __builtin_amdgcn_mfma_f32_16x16x16bf16_1k(pf, vf1, o1, 0, 0, 0);
      o2 = __builtin_amdgcn_mfma_f32_16x16x16bf16_1k(pf, vf2, o2, 0, 0, 0);
      o3 = __builtin_amdgcn_mfma_f32_16x16x16bf16_1k(pf, vf3, o3, 0, 0, 0);
    }
  }

  // reduce l over quads (keys were split by quad), then invert per O-row
  l_run += __shfl_xor(l_run, 16);
  l_run += __shfl_xor(l_run, 32);
  const float il0 = 1.f / __shfl(l_run, quad * 4 + 0);
  const float il1 = 1.f / __shfl(l_run, quad * 4 + 1);
  const float il2 = 1.f / __shfl(l_run, quad * 4 + 2);
  const float il3 = 1.f / __shfl(l_run, quad * 4 + 3);

  const int rowbase = qt * 128 + wave * 16 + quad * 4;
  const f4* oc[4] = {&o0, &o1, &o2, &o3};
  const float il[4] = {il0, il1, il2, il3};
  const size_t off0 = ((size_t)bz * 2048 + rowbase) * 1024 + hy * 64 + l15;
#pragma unroll
  for (int c = 0; c < 4; ++c)
#pragma unroll
    for (int r = 0; r < 4; ++r)
      attH[off0 + (size_t)r * 1024 + c * 16] = f2bf((*oc[c])[r] * il[r]);
}

// ---------------------------------------------------------------------------
// attn v2 (global-load variant) for Tier C only: fp32 att into d_out slice.
// ---------------------------------------------------------------------------
__global__ __launch_bounds__(256) void attn_c(
    const short* __restrict__ Qp, const short* __restrict__ Kp,
    const short* __restrict__ Vtp, const float* __restrict__ q2a,
    const float* __restrict__ k2a, float* __restrict__ attF, int col0) {
  const int t = threadIdx.x;
  const int wave = t >> 6;
  const int lane = t & 63;
  const int l15 = lane & 15;
  const int quad = lane >> 4;
  const int hy = blockIdx.y;
  const int qt = blockIdx.x;
  const size_t base = (size_t)hy * 2048;
  const int qrow = qt * 64 + wave * 16 + l15;

  const short* qp = Qp + (base + qrow) * 64 + quad * 8;
  const sh8 qf0 = *(const sh8*)qp;
  const sh8 qf1 = *(const sh8*)(qp + 32);
  const float q2 = q2a[base + qrow];

  float l_run = 0.f;
  f4 o0 = (f4){0.f, 0.f, 0.f, 0.f}, o1 = o0, o2 = o0, o3 = o0;

  const short* kbase = Kp + (base + l15) * 64 + quad * 8;
  const float* k2p = k2a + base + quad * 4;
  const short* vbase = Vtp + ((size_t)hy * 64 + l15) * 2048 + quad * 4;

  for (int j = 0; j < 2048; j += 16) {
    const sh8 kf0 = *(const sh8*)(kbase + (size_t)j * 64);
    const sh8 kf1 = *(const sh8*)(kbase + (size_t)j * 64 + 32);
    f4 st = (f4){0.f, 0.f, 0.f, 0.f};
    st = __builtin_amdgcn_mfma_f32_16x16x32_bf16(kf0, qf0, st, 0, 0, 0);
    st = __builtin_amdgcn_mfma_f32_16x16x32_bf16(kf1, qf1, st, 0, 0, 0);
    const f4 k2v = *(const f4*)(k2p + j);
    float p[4];
#pragma unroll
    for (int r = 0; r < 4; ++r) {
      const float d2 = fmaxf(fmaf(-2.f, st[r], q2 + k2v[r]), 1e-12f);
      p[r] = __expf(-sqrtf(d2));
    }
    l_run += (p[0] + p[1]) + (p[2] + p[3]);
    sh4 pf;
#pragma unroll
    for (int r = 0; r < 4; ++r) pf[r] = f2bf(p[r]);
    const sh4 vf0 = *(const sh4*)(vbase + j);
    const sh4 vf1 = *(const sh4*)(vbase + 16 * 2048 + j);
    const sh4 vf2 = *(const sh4*)(vbase + 32 * 2048 + j);
    const sh4 vf3 = *(const sh4*)(vbase + 48 * 2048 + j);
    o0 = __builtin_amdgcn_mfma_f32_16x16x16bf16_1k(pf, vf0, o0, 0, 0, 0);
    o1 = __builtin_amdgcn_mfma_f32_16x16x16bf16_1k(pf, vf1, o1, 0, 0, 0);
    o2 = __builtin_amdgcn_mfma_f32_16x16x16bf16_1k(pf, vf2, o2, 0, 0, 0);
    o3 = __builtin_amdgcn_mfma_f32_16x16x16bf16_1k(pf, vf3, o3, 0, 0, 0);
  }

  l_run += __shfl_xor(l_run, 16);
  l_run += __shfl_xor(l_run, 32);
  const float il0 = 1.f / __shfl(l_run, quad * 4 + 0);
  const float il1 = 1.f / __shfl(l_run, quad * 4 + 1);
  const float il2 = 1.f / __shfl(l_run, quad * 4 + 2);
  const float il3 = 1.f / __shfl(l_run, quad * 4 + 3);

  const int rowbase = qt * 64 + wave * 16 + quad * 4;
  const f4* oc[4] = {&o0, &o1, &o2, &o3};
  const float il[4] = {il0, il1, il2, il3};
  const size_t off0 = (size_t)rowbase * 1024 + col0 + hy * 64 + l15;
#pragma unroll
  for (int c = 0; c < 4; ++c)
#pragma unroll
    for (int r = 0; r < 4; ++r)
      attF[off0 + (size_t)r * 1024 + c * 16] = (*oc[c])[r] * il[r];
}

// ---------------------------------------------------------------------------
// Output projection, fp32 Wo (Tier A): GLDS A + pack8 B.
// ---------------------------------------------------------------------------
__global__ __launch_bounds__(256) void gemm_out_ws(
    const short* __restrict__ A, const float* __restrict__ W,
    const float* __restrict__ Bias, float* __restrict__ Out) {
  __shared__ short As[128 * 32];
  __shared__ short Bs[128 * 32];
  const int t = threadIdx.x;
  const int wave = t >> 6;
  const int lane = t & 63;
  const int l15 = lane & 15;
  const int quad = lane >> 4;
  const int m0 = blockIdx.y * 128;
  const int n0 = blockIdx.x * 128;
  const int wm = (wave & 1) * 64;
  const int wn = (wave >> 1) * 64;

  f4 acc[4][4];
#pragma unroll
  for (int i = 0; i < 4; ++i)
#pragma unroll
    for (int j = 0; j < 4; ++j) acc[i][j] = (f4){0.f, 0.f, 0.f, 0.f};

  const short* ag = A + (size_t)(m0 + (t >> 2)) * 1024 + (t & 3) * 8;
  const float* bg = W + (size_t)(n0 + (t >> 2)) * 1024 + (t & 3) * 8;
  short* al = As + wave * 512;

  for (int kt = 0; kt < 1024; kt += 32) {
    const sh8 b0 = pack8(*(const f4*)(bg + kt), *(const f4*)(bg + kt + 4));
    const sh8 b1 =
        pack8(*(const f4*)(bg + 65536 + kt), *(const f4*)(bg + 65536 + kt + 4));
    __syncthreads();
    GLDS16(ag + kt, al);
    GLDS16(ag + 65536 + kt, al + 2048);
    *(sh8*)(Bs + t * 8) = b0;
    *(sh8*)(Bs + 2048 + t * 8) = b1;
    __syncthreads();
    sh8 af[4], bf[4];
#pragma unroll
    for (int i = 0; i < 4; ++i) {
      af[i] = *(const sh8*)(As + (wm + i * 16 + l15) * 32 + quad * 8);
      bf[i] = *(const sh8*)(Bs + (wn + i * 16 + l15) * 32 + quad * 8);
    }
#pragma unroll
    for (int i = 0; i < 4; ++i)
#pragma unroll
      for (int j = 0; j < 4; ++j)
        acc[i][j] =
            __builtin_amdgcn_mfma_f32_16x16x32_bf16(af[i], bf[j], acc[i][j], 0, 0, 0);
  }

#pragma unroll
  for (int j = 0; j < 4; ++j) {
    const int n = n0 + wn + j * 16 + l15;
    const float bias = Bias[n];
#pragma unroll
    for (int i = 0; i < 4; ++i) {
#pragma unroll
      for (int r = 0; r < 4; ++r) {
        const int m = m0 + wm + i * 16 + quad * 4 + r;
        Out[(size_t)m * 1024 + n] = acc[i][j][r] + bias;
      }
    }
  }
}

// ---------------------------------------------------------------------------
// Output projection, bf16 Wo (Tier A2): GLDS both operands.
// ---------------------------------------------------------------------------
__global__ __launch_bounds__(256) void gemm_out_bf(
    const short* __restrict__ A, const short* __restrict__ W,
    const float* __restrict__ Bias, float* __restrict__ Out) {
  __shared__ short As[128 * 32];
  __shared__ short Bs[128 * 32];
  const int t = threadIdx.x;
  const int wave = t >> 6;
  const int lane = t & 63;
  const int l15 = lane & 15;
  const int quad = lane >> 4;
  const int m0 = blockIdx.y * 128;
  const int n0 = blockIdx.x * 128;
  const int wm = (wave & 1) * 64;
  const int wn = (wave >> 1) * 64;

  f4 acc[4][4];
#pragma unroll
  for (int i = 0; i < 4; ++i)
#pragma unroll
    for (int j = 0; j < 4; ++j) acc[i][j] = (f4){0.f, 0.f, 0.f, 0.f};

  const short* ag = A + (size_t)(m0 + (t >> 2)) * 1024 + (t & 3) * 8;
  const short* bg = W + (size_t)(n0 + (t >> 2)) * 1024 + (t & 3) * 8;
  short* al = As + wave * 512;
  short* bl = Bs + wave * 512;

  for (int kt = 0; kt < 1024; kt += 32) {
    __syncthreads();
    GLDS16(ag + kt, al);
    GLDS16(ag + 65536 + kt, al + 2048);
    GLDS16(bg + kt, bl);
    GLDS16(bg + 65536 + kt, bl + 2048);
    __syncthreads();
    sh8 af[4], bf[4];
#pragma unroll
    for (int i = 0; i < 4; ++i) {
      af[i] = *(const sh8*)(As + (wm + i * 16 + l15) * 32 + quad * 8);
      bf[i] = *(const sh8*)(Bs + (wn + i * 16 + l15) * 32 + quad * 8);
    }
#pragma unroll
    for (int i = 0; i < 4; ++i)
#pragma unroll
      for (int j = 0; j < 4; ++j)
        acc[i][j] =
            __builtin_amdgcn_mfma_f32_16x16x32_bf16(af[i], bf[j], acc[i][j], 0, 0, 0);
  }

#pragma unroll
  for (int j = 0; j < 4; ++j) {
    const int n = n0 + wn + j * 16 + l15;
    const float bias = Bias[n];
#pragma unroll
    for (int i = 0; i < 4; ++i) {
#pragma unroll
      for (int r = 0; r < 4; ++r) {
        const int m = m0 + wm + i * 16 + quad * 4 + r;
        Out[(size_t)m * 1024 + n] = acc[i][j][r] + bias;
      }
    }
  }
}

// ---------------------------------------------------------------------------
// Fallback in-place output projection (Tier C).
// ---------------------------------------------------------------------------
__global__ __launch_bounds__(256) void outproj_inplace(
    float* __restrict__ AO, const float* __restrict__ W,
    const float* __restrict__ Bias) {
  __shared__ short attS[16 * 264];
  const int t = threadIdx.x;
  const int wave = t >> 6;
  const int lane = t & 63;
  const int l15 = lane & 15;
  const int quad = lane >> 4;
  const int m0 = blockIdx.x * 16;
  const int n0w = wave * 256;

  f4 acc[16];
#pragma unroll
  for (int i = 0; i < 16; ++i) acc[i] = (f4){0.f, 0.f, 0.f, 0.f};

  for (int kc = 0; kc < 4; ++kc) {
    __syncthreads();
#pragma unroll
    for (int i = 0; i < 2; ++i) {
      const int e = i * 2048 + t * 8;
      const int row = e >> 8;
      const int col = e & 255;
      const float* src = AO + (size_t)(m0 + row) * 1024 + kc * 256 + col;
      *(sh8*)(attS + row * 264 + col) =
          pack8(*(const f4*)src, *(const f4*)(src + 4));
    }
    __syncthreads();
    for (int ktl = 0; ktl < 256; ktl += 32) {
      const sh8 af = *(const sh8*)(attS + l15 * 264 + ktl + quad * 8);
      const int kt = kc * 256 + ktl;
#pragma unroll
      for (int nf = 0; nf < 16; ++nf) {
        const float* wp = W + (size_t)(n0w + nf * 16 + l15) * 1024 + kt + quad * 8;
        const sh8 bf = pack8(*(const f4*)wp, *(const f4*)(wp + 4));
        acc[nf] = __builtin_amdgcn_mfma_f32_16x16x32_bf16(af, bf, acc[nf], 0, 0, 0);
      }
    }
  }
  __syncthreads();

#pragma unroll
  for (int nf = 0; nf < 16; ++nf) {
    const int n = n0w + nf * 16 + l15;
    const float bias = Bias[n];
#pragma unroll
    for (int r = 0; r < 4; ++r) {
      const int m = m0 + quad * 4 + r;
      AO[(size_t)m * 1024 + n] = acc[nf][r] + bias;
    }
  }
}

// ---------------------------------------------------------------------------
extern "C" void kernel_launch(void* const* d_in, const int* in_sizes, int n_in,
                              void* d_out, int out_size, void* d_ws,
                              size_t ws_size, hipStream_t stream) {
  const float* x = (const float*)d_in[0];
  const float* wq = (const float*)d_in[1];
  const float* bq = (const float*)d_in[2];
  const float* wk = (const float*)d_in[3];
  const float* bk = (const float*)d_in[4];
  const float* wv = (const float*)d_in[5];
  const float* bv = (const float*)d_in[6];
  const float* wo = (const float*)d_in[7];
  const float* bo = (const float*)d_in[8];
  float* out = (float*)d_out;

  const size_t NEED_A2 = 50855936ULL;  // A + Xbf 8MB + Wbf 8MB
  const size_t NEED_A = 34078720ULL;   // 24MB QKV(2b) + 8MB att + 512KB q2k2

  if (ws_size >= NEED_A) {
    short* Qp = (short*)d_ws;                 // [b*16+h][2048][64] bf16, 8MB
    short* Kp = Qp + 4194304;                 // 8MB
    short* Vtp = Kp + 4194304;                // [b*16+h][64][2048] bf16, 8MB
    short* attAll = Vtp + 4194304;            // [4096][1024] bf16, 8MB
    float* q2 = (float*)(attAll + 4194304);   // 256KB
    float* k2 = q2 + 65536;                   // 256KB

    if (ws_size >= NEED_A2) {
      short* Xb = (short*)(k2 + 65536);       // 4M bf16 = 8MB
      short* Wqb = Xb + 4194304;              // 1M bf16 = 2MB each
      short* Wkb = Wqb + 1048576;
      short* Wvb = Wkb + 1048576;
      short* Wob = Wvb + 1048576;
      cvt_bf16<<<2048, 256, 0, stream>>>(x, Xb, 4194304);
      cvt_bf16<<<512, 256, 0, stream>>>(wq, Wqb, 1048576);
      cvt_bf16<<<512, 256, 0, stream>>>(wk, Wkb, 1048576);
      cvt_bf16<<<512, 256, 0, stream>>>(wv, Wvb, 1048576);
      cvt_bf16<<<512, 256, 0, stream>>>(wo, Wob, 1048576);
      for (int b = 0; b < 2; ++b)
        gemm_qkv_bf<<<dim3(24, 16), 256, 0, stream>>>(
            Xb + (size_t)b * 2097152, Wqb, bq, Wkb, bk, Wvb, bv,
            Qp + (size_t)b * 2097152, Kp + (size_t)b * 2097152,
            Vtp + (size_t)b * 2097152);
      sumsq<<<512, 256, 0, stream>>>(Qp, Kp, q2, k2, 65536);
      attn3<<<dim3(16, 16, 2), 512, 0, stream>>>(Qp, Kp, Vtp, q2, k2, attAll);
      gemm_out_bf<<<dim3(8, 32), 256, 0, stream>>>(attAll, Wob, bo, out);
    } else {
      for (int b = 0; b < 2; ++b)
        gemm_qkvp<<<dim3(24, 16), 256, 0, stream>>>(
            x + (size_t)b * 2097152, wq, bq, wk, bk, wv, bv,
            Qp + (size_t)b * 2097152, Kp + (size_t)b * 2097152,
            Vtp + (size_t)b * 2097152, 0, 8);
      sumsq<<<512, 256, 0, stream>>>(Qp, Kp, q2, k2, 65536);
      attn3<<<dim3(16, 16, 2), 512, 0, stream>>>(Qp, Kp, Vtp, q2, k2, attAll);
      gemm_out_ws<<<dim3(8, 32), 256, 0, stream>>>(attAll, wo, bo, out);
    }
  } else {
    // Tier C: small-ws fallback (att fp32 in d_out, in-place outproj).
    int G = 16;
    while (G > 2 && (size_t)G * 802816ULL > ws_size) G >>= 1;
    short* Qp = (short*)d_ws;
    short* Kp = Qp + (size_t)G * 131072;
    short* Vtp = Kp + (size_t)G * 131072;
    float* q2 = (float*)(Vtp + (size_t)G * 131072);
    float* k2 = q2 + (size_t)G * 2048;

    const int groups = 16 / G;
    for (int b = 0; b < 2; ++b) {
      const float* xb = x + (size_t)b * 2097152;
      float* attB = out + (size_t)b * 2097152;
      for (int g = 0; g < groups; ++g) {
        gemm_qkvp<<<dim3(3 * (G / 2), 16), 256, 0, stream>>>(
            xb, wq, bq, wk, bk, wv, bv, Qp, Kp, Vtp, g * G * 64, G / 2);
        sumsq<<<16 * G, 256, 0, stream>>>(Qp, Kp, q2, k2, G * 2048);
        attn_c<<<dim3(32, G), 256, 0, stream>>>(Qp, Kp, Vtp, q2, k2, attB,
                                                g * G * 64);
      }
    }
    outproj_inplace<<<256, 256, 0, stream>>>(out, wo, bo);
  }
}

// Round 11
// 262.936 us; speedup vs baseline: 2.8037x; 1.1991x over previous
//
#include <hip/hip_runtime.h>

// L2 self-attention. Inputs/outputs FP32; compute bf16 MFMA, fp32 accumulate.
// B=2 N=2048 D=1024 H=16 hd=64.
// attn3 v2: LDS-staged flash attention + VALU diet: __builtin_amdgcn_sqrtf
// (raw v_sqrt_f32, no denorm fixup; NOTE __sqrtf collides with glibc math.h),
// half-up f2bf ((u+0x8000)>>16, 2 ops vs 5 for RNE).
// Fixed softmax max = 0 (scores <= 0 always).
// Tier A2 (ws>=48.5MB): X/W pre-converted to bf16 -> all GEMMs pure GLDS16.
// Tier A (>=32.5MB): fp32-staging GEMMs + attn3. Tier C: small-ws fallback.

typedef __attribute__((ext_vector_type(8))) short sh8;   // 8 bf16 (4 VGPRs)
typedef __attribute__((ext_vector_type(4))) short sh4;   // 4 bf16 (2 VGPRs)
typedef __attribute__((ext_vector_type(4))) float f4;    // 4 fp32

__device__ __forceinline__ float bf2f(short s) {
  union { unsigned u; float f; } c;
  c.u = ((unsigned)(unsigned short)s) << 16;
  return c.f;
}
// fast bf16 round: half-up (2 VALU ops). Tie behavior differs from RNE by
// <=1 ulp -- absmax budget 2.4e-3, measured headroom ~5x.
__device__ __forceinline__ short f2bf(float f) {
  union { float f; unsigned u; } c;
  c.f = f;
  return (short)((c.u + 0x8000u) >> 16);
}
__device__ __forceinline__ sh8 pack8(f4 a, f4 b) {
  sh8 r;
  r[0] = f2bf(a[0]); r[1] = f2bf(a[1]); r[2] = f2bf(a[2]); r[3] = f2bf(a[3]);
  r[4] = f2bf(b[0]); r[5] = f2bf(b[1]); r[6] = f2bf(b[2]); r[7] = f2bf(b[3]);
  return r;
}

// async global->LDS, 16B per lane; LDS dest = wave-uniform base + lane*16
#define GLDS16(g, l)                                                      \
  __builtin_amdgcn_global_load_lds(                                       \
      (__attribute__((address_space(1))) void*)(void*)(g),                \
      (__attribute__((address_space(3))) void*)(void*)(l), 16, 0, 0)

// ---------------------------------------------------------------------------
// fp32 -> bf16 elementwise (n multiple of 8)
// ---------------------------------------------------------------------------
__global__ __launch_bounds__(256) void cvt_bf16(const float* __restrict__ src,
                                                short* __restrict__ dst, int n) {
  const int i = (blockIdx.x * 256 + threadIdx.x) * 8;
  if (i < n)
    *(sh8*)(dst + i) = pack8(*(const f4*)(src + i), *(const f4*)(src + i + 4));
}

// ---------------------------------------------------------------------------
// QKV projection, fp32 inputs (Tier A): pack8 staging.
// ---------------------------------------------------------------------------
__global__ __launch_bounds__(256) void gemm_qkvp(
    const float* __restrict__ X, const float* __restrict__ Wq,
    const float* __restrict__ Bq, const float* __restrict__ Wk,
    const float* __restrict__ Bk, const float* __restrict__ Wv,
    const float* __restrict__ Bv, short* __restrict__ Qp,
    short* __restrict__ Kp, short* __restrict__ Vtp, int w0, int nblkP) {
  __shared__ short As[128 * 32];
  __shared__ short Bs[128 * 32];
  const int t = threadIdx.x;
  const int wave = t >> 6;
  const int lane = t & 63;
  const int l15 = lane & 15;
  const int quad = lane >> 4;
  const int m0 = blockIdx.y * 128;
  const int which = blockIdx.x / nblkP;
  const int n0l = (blockIdx.x % nblkP) * 128;
  const int wrow0 = w0 + n0l;
  const float* W = (which == 0) ? Wq : ((which == 1) ? Wk : Wv);
  const float* Bias = (which == 0) ? Bq : ((which == 1) ? Bk : Bv);
  const int wm = (wave & 1) * 64;
  const int wn = (wave >> 1) * 64;

  f4 acc[4][4];
#pragma unroll
  for (int i = 0; i < 4; ++i)
#pragma unroll
    for (int j = 0; j < 4; ++j) acc[i][j] = (f4){0.f, 0.f, 0.f, 0.f};

  const float* ag = X + (size_t)(m0 + (t >> 2)) * 1024 + (t & 3) * 8;
  const float* bg = W + (size_t)(wrow0 + (t >> 2)) * 1024 + (t & 3) * 8;

  for (int kt = 0; kt < 1024; kt += 32) {
    const sh8 a0 = pack8(*(const f4*)(ag + kt), *(const f4*)(ag + kt + 4));
    const sh8 a1 =
        pack8(*(const f4*)(ag + 65536 + kt), *(const f4*)(ag + 65536 + kt + 4));
    const sh8 b0 = pack8(*(const f4*)(bg + kt), *(const f4*)(bg + kt + 4));
    const sh8 b1 =
        pack8(*(const f4*)(bg + 65536 + kt), *(const f4*)(bg + 65536 + kt + 4));
    __syncthreads();
    *(sh8*)(As + t * 8) = a0;
    *(sh8*)(As + 2048 + t * 8) = a1;
    *(sh8*)(Bs + t * 8) = b0;
    *(sh8*)(Bs + 2048 + t * 8) = b1;
    __syncthreads();
    sh8 af[4], bf[4];
#pragma unroll
    for (int i = 0; i < 4; ++i) {
      af[i] = *(const sh8*)(As + (wm + i * 16 + l15) * 32 + quad * 8);
      bf[i] = *(const sh8*)(Bs + (wn + i * 16 + l15) * 32 + quad * 8);
    }
#pragma unroll
    for (int i = 0; i < 4; ++i)
#pragma unroll
      for (int j = 0; j < 4; ++j)
        acc[i][j] =
            __builtin_amdgcn_mfma_f32_16x16x32_bf16(af[i], bf[j], acc[i][j], 0, 0, 0);
  }

#pragma unroll
  for (int j = 0; j < 4; ++j) {
    const int ngl = n0l + wn + j * 16 + l15;
    const float bias = Bias[w0 + ngl];
    const int hl = ngl >> 6;
    const int d = ngl & 63;
#pragma unroll
    for (int i = 0; i < 4; ++i) {
#pragma unroll
      for (int r = 0; r < 4; ++r) {
        const int m = m0 + wm + i * 16 + quad * 4 + r;
        const short o = f2bf(acc[i][j][r] + bias);
        if (which == 0)
          Qp[((size_t)hl * 2048 + m) * 64 + d] = o;
        else if (which == 1)
          Kp[((size_t)hl * 2048 + m) * 64 + d] = o;
        else
          Vtp[((size_t)hl * 64 + d) * 2048 + m] = o;
      }
    }
  }
}

// ---------------------------------------------------------------------------
// QKV projection, bf16 pre-converted inputs (Tier A2): GLDS16 both operands.
// ---------------------------------------------------------------------------
__global__ __launch_bounds__(256) void gemm_qkv_bf(
    const short* __restrict__ X, const short* __restrict__ Wq,
    const float* __restrict__ Bq, const short* __restrict__ Wk,
    const float* __restrict__ Bk, const short* __restrict__ Wv,
    const float* __restrict__ Bv, short* __restrict__ Qp,
    short* __restrict__ Kp, short* __restrict__ Vtp) {
  __shared__ short As[128 * 32];
  __shared__ short Bs[128 * 32];
  const int t = threadIdx.x;
  const int wave = t >> 6;
  const int lane = t & 63;
  const int l15 = lane & 15;
  const int quad = lane >> 4;
  const int m0 = blockIdx.y * 128;
  const int which = blockIdx.x >> 3;     // 0=Q 1=K 2=V
  const int n0l = (blockIdx.x & 7) * 128;
  const short* W = (which == 0) ? Wq : ((which == 1) ? Wk : Wv);
  const float* Bias = (which == 0) ? Bq : ((which == 1) ? Bk : Bv);
  const int wm = (wave & 1) * 64;
  const int wn = (wave >> 1) * 64;

  f4 acc[4][4];
#pragma unroll
  for (int i = 0; i < 4; ++i)
#pragma unroll
    for (int j = 0; j < 4; ++j) acc[i][j] = (f4){0.f, 0.f, 0.f, 0.f};

  const short* ag = X + (size_t)(m0 + (t >> 2)) * 1024 + (t & 3) * 8;
  const short* bg = W + (size_t)(n0l + (t >> 2)) * 1024 + (t & 3) * 8;
  short* al = As + wave * 512;
  short* bl = Bs + wave * 512;

  for (int kt = 0; kt < 1024; kt += 32) {
    __syncthreads();
    GLDS16(ag + kt, al);
    GLDS16(ag + 65536 + kt, al + 2048);
    GLDS16(bg + kt, bl);
    GLDS16(bg + 65536 + kt, bl + 2048);
    __syncthreads();
    sh8 af[4], bf[4];
#pragma unroll
    for (int i = 0; i < 4; ++i) {
      af[i] = *(const sh8*)(As + (wm + i * 16 + l15) * 32 + quad * 8);
      bf[i] = *(const sh8*)(Bs + (wn + i * 16 + l15) * 32 + quad * 8);
    }
#pragma unroll
    for (int i = 0; i < 4; ++i)
#pragma unroll
      for (int j = 0; j < 4; ++j)
        acc[i][j] =
            __builtin_amdgcn_mfma_f32_16x16x32_bf16(af[i], bf[j], acc[i][j], 0, 0, 0);
  }

#pragma unroll
  for (int j = 0; j < 4; ++j) {
    const int ngl = n0l + wn + j * 16 + l15;
    const float bias = Bias[ngl];
    const int hl = ngl >> 6;
    const int d = ngl & 63;
#pragma unroll
    for (int i = 0; i < 4; ++i) {
#pragma unroll
      for (int r = 0; r < 4; ++r) {
        const int m = m0 + wm + i * 16 + quad * 4 + r;
        const short o = f2bf(acc[i][j][r] + bias);
        if (which == 0)
          Qp[((size_t)hl * 2048 + m) * 64 + d] = o;
        else if (which == 1)
          Kp[((size_t)hl * 2048 + m) * 64 + d] = o;
        else
          Vtp[((size_t)hl * 64 + d) * 2048 + m] = o;
      }
    }
  }
}

// ---------------------------------------------------------------------------
// Sums of squares of bf16-rounded Q and K rows. R rows per tensor.
// ---------------------------------------------------------------------------
__global__ __launch_bounds__(256) void sumsq(const short* __restrict__ Qp,
                                             const short* __restrict__ Kp,
                                             float* __restrict__ q2a,
                                             float* __restrict__ k2a, int R) {
  const int tid = blockIdx.x * 256 + threadIdx.x;
  const bool isQ = tid < R;
  const int r = isQ ? tid : tid - R;
  const short* p = (isQ ? Qp : Kp) + (size_t)r * 64;
  float s = 0.f;
#pragma unroll
  for (int i = 0; i < 8; ++i) {
    sh8 v = *(const sh8*)(p + i * 8);
#pragma unroll
    for (int j = 0; j < 8; ++j) {
      float f = bf2f(v[j]);
      s = fmaf(f, f, s);
    }
  }
  (isQ ? q2a : k2a)[r] = s;
}

// ---------------------------------------------------------------------------
// attn3 v2: LDS-staged flash attention, fixed max=0, fast-math scalar path.
// Block = 8 waves = 128 queries; K-tiles of 128 staged to LDS (Ks stride 72,
// Vs stride 136). Wave owns 16 queries.
// S^T = MFMA(A=Kfrag, B=Qfrag): C row=key(quad*4+r), col=query(l15) ==
// A-layout of P for 16x16x16 PV. O C-layout: row=query, col=vdim chunk.
// ---------------------------------------------------------------------------
__global__ __launch_bounds__(512, 4) void attn3(
    const short* __restrict__ Qp, const short* __restrict__ Kp,
    const short* __restrict__ Vtp, const float* __restrict__ q2a,
    const float* __restrict__ k2a, short* __restrict__ attH) {
  __shared__ short Ks[128 * 72];   // [key][64 dims + 8 pad] = 18 KB
  __shared__ short Vs[64 * 136];   // [dim][128 keys + 8 pad] = 17 KB
  const int t = threadIdx.x;
  const int wave = t >> 6;
  const int lane = t & 63;
  const int l15 = lane & 15;
  const int quad = lane >> 4;
  const int hy = blockIdx.y;
  const int qt = blockIdx.x;       // 0..15 (128 queries each)
  const int bz = blockIdx.z;
  const size_t hb = (size_t)bz * gridDim.y + hy;
  const size_t base = hb * 2048;
  const int qrow = qt * 128 + wave * 16 + l15;

  const short* qp = Qp + (base + qrow) * 64 + quad * 8;
  const sh8 qf0 = *(const sh8*)qp;
  const sh8 qf1 = *(const sh8*)(qp + 32);
  const float q2 = q2a[base + qrow];

  float l_run = 0.f;
  f4 o0 = (f4){0.f, 0.f, 0.f, 0.f}, o1 = o0, o2 = o0, o3 = o0;

  const float* k2p = k2a + base + quad * 4;

  for (int k0 = 0; k0 < 2048; k0 += 128) {
    // --- stage K (128x64) and Vt (64x128) tiles, coalesced sh8 loads ---
    sh8 kv0, kv1, vv0, vv1;
    {
      const short* kg = Kp + (base + k0 + (t >> 3)) * 64 + (t & 7) * 8;
      kv0 = *(const sh8*)kg;
      kv1 = *(const sh8*)(kg + 64 * 64);
      const short* vg =
          Vtp + (hb * 64 + (t >> 4)) * 2048 + k0 + (t & 15) * 8;
      vv0 = *(const sh8*)vg;
      vv1 = *(const sh8*)(vg + 32 * 2048);
    }
    __syncthreads();  // prior sub-tile reads complete
    *(sh8*)(Ks + (t >> 3) * 72 + (t & 7) * 8) = kv0;
    *(sh8*)(Ks + (64 + (t >> 3)) * 72 + (t & 7) * 8) = kv1;
    *(sh8*)(Vs + (t >> 4) * 136 + (t & 15) * 8) = vv0;
    *(sh8*)(Vs + (32 + (t >> 4)) * 136 + (t & 15) * 8) = vv1;
    __syncthreads();

    // --- 8 sub-tiles of 16 keys ---
#pragma unroll
    for (int sub = 0; sub < 8; ++sub) {
      const int j = sub * 16;
      const sh8 kf0 = *(const sh8*)(Ks + (j + l15) * 72 + quad * 8);
      const sh8 kf1 = *(const sh8*)(Ks + (j + l15) * 72 + 32 + quad * 8);
      f4 st = (f4){0.f, 0.f, 0.f, 0.f};
      st = __builtin_amdgcn_mfma_f32_16x16x32_bf16(kf0, qf0, st, 0, 0, 0);
      st = __builtin_amdgcn_mfma_f32_16x16x32_bf16(kf1, qf1, st, 0, 0, 0);
      const f4 k2v = *(const f4*)(k2p + k0 + j);
      float p[4];
#pragma unroll
      for (int r = 0; r < 4; ++r) {
        const float d2 = fmaxf(fmaf(-2.f, st[r], q2 + k2v[r]), 1e-12f);
        p[r] = __expf(-__builtin_amdgcn_sqrtf(d2));  // raw v_sqrt + v_exp
      }
      l_run += (p[0] + p[1]) + (p[2] + p[3]);
      sh4 pf;
#pragma unroll
      for (int r = 0; r < 4; ++r) pf[r] = f2bf(p[r]);
      const sh4 vf0 = *(const sh4*)(Vs + l15 * 136 + j + quad * 4);
      const sh4 vf1 = *(const sh4*)(Vs + (l15 + 16) * 136 + j + quad * 4);
      const sh4 vf2 = *(const sh4*)(Vs + (l15 + 32) * 136 + j + quad * 4);
      const sh4 vf3 = *(const sh4*)(Vs + (l15 + 48) * 136 + j + quad * 4);
      o0 = __builtin_amdgcn_mfma_f32_16x16x16bf16_1k(pf, vf0, o0, 0, 0, 0);
      o1 = __builtin_amdgcn_mfma_f32_16x16x16bf16_1k(pf, vf1, o1, 0, 0, 0);
      o2 = __builtin_amdgcn_mfma_f32_16x16x16bf16_1k(pf, vf2, o2, 0, 0, 0);
      o3 = __builtin_amdgcn_mfma_f32_16x16x16bf16_1k(pf, vf3, o3, 0, 0, 0);
    }
  }

  // reduce l over quads (keys were split by quad), then invert per O-row
  l_run += __shfl_xor(l_run, 16);
  l_run += __shfl_xor(l_run, 32);
  const float il0 = 1.f / __shfl(l_run, quad * 4 + 0);
  const float il1 = 1.f / __shfl(l_run, quad * 4 + 1);
  const float il2 = 1.f / __shfl(l_run, quad * 4 + 2);
  const float il3 = 1.f / __shfl(l_run, quad * 4 + 3);

  const int rowbase = qt * 128 + wave * 16 + quad * 4;
  const f4* oc[4] = {&o0, &o1, &o2, &o3};
  const float il[4] = {il0, il1, il2, il3};
  const size_t off0 = ((size_t)bz * 2048 + rowbase) * 1024 + hy * 64 + l15;
#pragma unroll
  for (int c = 0; c < 4; ++c)
#pragma unroll
    for (int r = 0; r < 4; ++r)
      attH[off0 + (size_t)r * 1024 + c * 16] = f2bf((*oc[c])[r] * il[r]);
}

// ---------------------------------------------------------------------------
// attn (global-load variant) for Tier C only: fp32 att into d_out slice.
// ---------------------------------------------------------------------------
__global__ __launch_bounds__(256) void attn_c(
    const short* __restrict__ Qp, const short* __restrict__ Kp,
    const short* __restrict__ Vtp, const float* __restrict__ q2a,
    const float* __restrict__ k2a, float* __restrict__ attF, int col0) {
  const int t = threadIdx.x;
  const int wave = t >> 6;
  const int lane = t & 63;
  const int l15 = lane & 15;
  const int quad = lane >> 4;
  const int hy = blockIdx.y;
  const int qt = blockIdx.x;
  const size_t base = (size_t)hy * 2048;
  const int qrow = qt * 64 + wave * 16 + l15;

  const short* qp = Qp + (base + qrow) * 64 + quad * 8;
  const sh8 qf0 = *(const sh8*)qp;
  const sh8 qf1 = *(const sh8*)(qp + 32);
  const float q2 = q2a[base + qrow];

  float l_run = 0.f;
  f4 o0 = (f4){0.f, 0.f, 0.f, 0.f}, o1 = o0, o2 = o0, o3 = o0;

  const short* kbase = Kp + (base + l15) * 64 + quad * 8;
  const float* k2p = k2a + base + quad * 4;
  const short* vbase = Vtp + ((size_t)hy * 64 + l15) * 2048 + quad * 4;

  for (int j = 0; j < 2048; j += 16) {
    const sh8 kf0 = *(const sh8*)(kbase + (size_t)j * 64);
    const sh8 kf1 = *(const sh8*)(kbase + (size_t)j * 64 + 32);
    f4 st = (f4){0.f, 0.f, 0.f, 0.f};
    st = __builtin_amdgcn_mfma_f32_16x16x32_bf16(kf0, qf0, st, 0, 0, 0);
    st = __builtin_amdgcn_mfma_f32_16x16x32_bf16(kf1, qf1, st, 0, 0, 0);
    const f4 k2v = *(const f4*)(k2p + j);
    float p[4];
#pragma unroll
    for (int r = 0; r < 4; ++r) {
      const float d2 = fmaxf(fmaf(-2.f, st[r], q2 + k2v[r]), 1e-12f);
      p[r] = __expf(-__builtin_amdgcn_sqrtf(d2));
    }
    l_run += (p[0] + p[1]) + (p[2] + p[3]);
    sh4 pf;
#pragma unroll
    for (int r = 0; r < 4; ++r) pf[r] = f2bf(p[r]);
    const sh4 vf0 = *(const sh4*)(vbase + j);
    const sh4 vf1 = *(const sh4*)(vbase + 16 * 2048 + j);
    const sh4 vf2 = *(const sh4*)(vbase + 32 * 2048 + j);
    const sh4 vf3 = *(const sh4*)(vbase + 48 * 2048 + j);
    o0 = __builtin_amdgcn_mfma_f32_16x16x16bf16_1k(pf, vf0, o0, 0, 0, 0);
    o1 = __builtin_amdgcn_mfma_f32_16x16x16bf16_1k(pf, vf1, o1, 0, 0, 0);
    o2 = __builtin_amdgcn_mfma_f32_16x16x16bf16_1k(pf, vf2, o2, 0, 0, 0);
    o3 = __builtin_amdgcn_mfma_f32_16x16x16bf16_1k(pf, vf3, o3, 0, 0, 0);
  }

  l_run += __shfl_xor(l_run, 16);
  l_run += __shfl_xor(l_run, 32);
  const float il0 = 1.f / __shfl(l_run, quad * 4 + 0);
  const float il1 = 1.f / __shfl(l_run, quad * 4 + 1);
  const float il2 = 1.f / __shfl(l_run, quad * 4 + 2);
  const float il3 = 1.f / __shfl(l_run, quad * 4 + 3);

  const int rowbase = qt * 64 + wave * 16 + quad * 4;
  const f4* oc[4] = {&o0, &o1, &o2, &o3};
  const float il[4] = {il0, il1, il2, il3};
  const size_t off0 = (size_t)rowbase * 1024 + col0 + hy * 64 + l15;
#pragma unroll
  for (int c = 0; c < 4; ++c)
#pragma unroll
    for (int r = 0; r < 4; ++r)
      attF[off0 + (size_t)r * 1024 + c * 16] = (*oc[c])[r] * il[r];
}

// ---------------------------------------------------------------------------
// Output projection, fp32 Wo (Tier A): GLDS A + pack8 B.
// ---------------------------------------------------------------------------
__global__ __launch_bounds__(256) void gemm_out_ws(
    const short* __restrict__ A, const float* __restrict__ W,
    const float* __restrict__ Bias, float* __restrict__ Out) {
  __shared__ short As[128 * 32];
  __shared__ short Bs[128 * 32];
  const int t = threadIdx.x;
  const int wave = t >> 6;
  const int lane = t & 63;
  const int l15 = lane & 15;
  const int quad = lane >> 4;
  const int m0 = blockIdx.y * 128;
  const int n0 = blockIdx.x * 128;
  const int wm = (wave & 1) * 64;
  const int wn = (wave >> 1) * 64;

  f4 acc[4][4];
#pragma unroll
  for (int i = 0; i < 4; ++i)
#pragma unroll
    for (int j = 0; j < 4; ++j) acc[i][j] = (f4){0.f, 0.f, 0.f, 0.f};

  const short* ag = A + (size_t)(m0 + (t >> 2)) * 1024 + (t & 3) * 8;
  const float* bg = W + (size_t)(n0 + (t >> 2)) * 1024 + (t & 3) * 8;
  short* al = As + wave * 512;

  for (int kt = 0; kt < 1024; kt += 32) {
    const sh8 b0 = pack8(*(const f4*)(bg + kt), *(const f4*)(bg + kt + 4));
    const sh8 b1 =
        pack8(*(const f4*)(bg + 65536 + kt), *(const f4*)(bg + 65536 + kt + 4));
    __syncthreads();
    GLDS16(ag + kt, al);
    GLDS16(ag + 65536 + kt, al + 2048);
    *(sh8*)(Bs + t * 8) = b0;
    *(sh8*)(Bs + 2048 + t * 8) = b1;
    __syncthreads();
    sh8 af[4], bf[4];
#pragma unroll
    for (int i = 0; i < 4; ++i) {
      af[i] = *(const sh8*)(As + (wm + i * 16 + l15) * 32 + quad * 8);
      bf[i] = *(const sh8*)(Bs + (wn + i * 16 + l15) * 32 + quad * 8);
    }
#pragma unroll
    for (int i = 0; i < 4; ++i)
#pragma unroll
      for (int j = 0; j < 4; ++j)
        acc[i][j] =
            __builtin_amdgcn_mfma_f32_16x16x32_bf16(af[i], bf[j], acc[i][j], 0, 0, 0);
  }

#pragma unroll
  for (int j = 0; j < 4; ++j) {
    const int n = n0 + wn + j * 16 + l15;
    const float bias = Bias[n];
#pragma unroll
    for (int i = 0; i < 4; ++i) {
#pragma unroll
      for (int r = 0; r < 4; ++r) {
        const int m = m0 + wm + i * 16 + quad * 4 + r;
        Out[(size_t)m * 1024 + n] = acc[i][j][r] + bias;
      }
    }
  }
}

// ---------------------------------------------------------------------------
// Output projection, bf16 Wo (Tier A2): GLDS both operands.
// ---------------------------------------------------------------------------
__global__ __launch_bounds__(256) void gemm_out_bf(
    const short* __restrict__ A, const short* __restrict__ W,
    const float* __restrict__ Bias, float* __restrict__ Out) {
  __shared__ short As[128 * 32];
  __shared__ short Bs[128 * 32];
  const int t = threadIdx.x;
  const int wave = t >> 6;
  const int lane = t & 63;
  const int l15 = lane & 15;
  const int quad = lane >> 4;
  const int m0 = blockIdx.y * 128;
  const int n0 = blockIdx.x * 128;
  const int wm = (wave & 1) * 64;
  const int wn = (wave >> 1) * 64;

  f4 acc[4][4];
#pragma unroll
  for (int i = 0; i < 4; ++i)
#pragma unroll
    for (int j = 0; j < 4; ++j) acc[i][j] = (f4){0.f, 0.f, 0.f, 0.f};

  const short* ag = A + (size_t)(m0 + (t >> 2)) * 1024 + (t & 3) * 8;
  const short* bg = W + (size_t)(n0 + (t >> 2)) * 1024 + (t & 3) * 8;
  short* al = As + wave * 512;
  short* bl = Bs + wave * 512;

  for (int kt = 0; kt < 1024; kt += 32) {
    __syncthreads();
    GLDS16(ag + kt, al);
    GLDS16(ag + 65536 + kt, al + 2048);
    GLDS16(bg + kt, bl);
    GLDS16(bg + 65536 + kt, bl + 2048);
    __syncthreads();
    sh8 af[4], bf[4];
#pragma unroll
    for (int i = 0; i < 4; ++i) {
      af[i] = *(const sh8*)(As + (wm + i * 16 + l15) * 32 + quad * 8);
      bf[i] = *(const sh8*)(Bs + (wn + i * 16 + l15) * 32 + quad * 8);
    }
#pragma unroll
    for (int i = 0; i < 4; ++i)
#pragma unroll
      for (int j = 0; j < 4; ++j)
        acc[i][j] =
            __builtin_amdgcn_mfma_f32_16x16x32_bf16(af[i], bf[j], acc[i][j], 0, 0, 0);
  }

#pragma unroll
  for (int j = 0; j < 4; ++j) {
    const int n = n0 + wn + j * 16 + l15;
    const float bias = Bias[n];
#pragma unroll
    for (int i = 0; i < 4; ++i) {
#pragma unroll
      for (int r = 0; r < 4; ++r) {
        const int m = m0 + wm + i * 16 + quad * 4 + r;
        Out[(size_t)m * 1024 + n] = acc[i][j][r] + bias;
      }
    }
  }
}

// ---------------------------------------------------------------------------
// Fallback in-place output projection (Tier C).
// ---------------------------------------------------------------------------
__global__ __launch_bounds__(256) void outproj_inplace(
    float* __restrict__ AO, const float* __restrict__ W,
    const float* __restrict__ Bias) {
  __shared__ short attS[16 * 264];
  const int t = threadIdx.x;
  const int wave = t >> 6;
  const int lane = t & 63;
  const int l15 = lane & 15;
  const int quad = lane >> 4;
  const int m0 = blockIdx.x * 16;
  const int n0w = wave * 256;

  f4 acc[16];
#pragma unroll
  for (int i = 0; i < 16; ++i) acc[i] = (f4){0.f, 0.f, 0.f, 0.f};

  for (int kc = 0; kc < 4; ++kc) {
    __syncthreads();
#pragma unroll
    for (int i = 0; i < 2; ++i) {
      const int e = i * 2048 + t * 8;
      const int row = e >> 8;
      const int col = e & 255;
      const float* src = AO + (size_t)(m0 + row) * 1024 + kc * 256 + col;
      *(sh8*)(attS + row * 264 + col) =
          pack8(*(const f4*)src, *(const f4*)(src + 4));
    }
    __syncthreads();
    for (int ktl = 0; ktl < 256; ktl += 32) {
      const sh8 af = *(const sh8*)(attS + l15 * 264 + ktl + quad * 8);
      const int kt = kc * 256 + ktl;
#pragma unroll
      for (int nf = 0; nf < 16; ++nf) {
        const float* wp = W + (size_t)(n0w + nf * 16 + l15) * 1024 + kt + quad * 8;
        const sh8 bf = pack8(*(const f4*)wp, *(const f4*)(wp + 4));
        acc[nf] = __builtin_amdgcn_mfma_f32_16x16x32_bf16(af, bf, acc[nf], 0, 0, 0);
      }
    }
  }
  __syncthreads();

#pragma unroll
  for (int nf = 0; nf < 16; ++nf) {
    const int n = n0w + nf * 16 + l15;
    const float bias = Bias[n];
#pragma unroll
    for (int r = 0; r < 4; ++r) {
      const int m = m0 + quad * 4 + r;
      AO[(size_t)m * 1024 + n] = acc[nf][r] + bias;
    }
  }
}

// ---------------------------------------------------------------------------
extern "C" void kernel_launch(void* const* d_in, const int* in_sizes, int n_in,
                              void* d_out, int out_size, void* d_ws,
                              size_t ws_size, hipStream_t stream) {
  const float* x = (const float*)d_in[0];
  const float* wq = (const float*)d_in[1];
  const float* bq = (const float*)d_in[2];
  const float* wk = (const float*)d_in[3];
  const float* bk = (const float*)d_in[4];
  const float* wv = (const float*)d_in[5];
  const float* bv = (const float*)d_in[6];
  const float* wo = (const float*)d_in[7];
  const float* bo = (const float*)d_in[8];
  float* out = (float*)d_out;

  const size_t NEED_A2 = 50855936ULL;  // A + Xbf 8MB + Wbf 8MB
  const size_t NEED_A = 34078720ULL;   // 24MB QKV(2b) + 8MB att + 512KB q2k2

  if (ws_size >= NEED_A) {
    short* Qp = (short*)d_ws;                 // [b*16+h][2048][64] bf16, 8MB
    short* Kp = Qp + 4194304;                 // 8MB
    short* Vtp = Kp + 4194304;                // [b*16+h][64][2048] bf16, 8MB
    short* attAll = Vtp + 4194304;            // [4096][1024] bf16, 8MB
    float* q2 = (float*)(attAll + 4194304);   // 256KB
    float* k2 = q2 + 65536;                   // 256KB

    if (ws_size >= NEED_A2) {
      short* Xb = (short*)(k2 + 65536);       // 4M bf16 = 8MB
      short* Wqb = Xb + 4194304;              // 1M bf16 = 2MB each
      short* Wkb = Wqb + 1048576;
      short* Wvb = Wkb + 1048576;
      short* Wob = Wvb + 1048576;
      cvt_bf16<<<2048, 256, 0, stream>>>(x, Xb, 4194304);
      cvt_bf16<<<512, 256, 0, stream>>>(wq, Wqb, 1048576);
      cvt_bf16<<<512, 256, 0, stream>>>(wk, Wkb, 1048576);
      cvt_bf16<<<512, 256, 0, stream>>>(wv, Wvb, 1048576);
      cvt_bf16<<<512, 256, 0, stream>>>(wo, Wob, 1048576);
      for (int b = 0; b < 2; ++b)
        gemm_qkv_bf<<<dim3(24, 16), 256, 0, stream>>>(
            Xb + (size_t)b * 2097152, Wqb, bq, Wkb, bk, Wvb, bv,
            Qp + (size_t)b * 2097152, Kp + (size_t)b * 2097152,
            Vtp + (size_t)b * 2097152);
      sumsq<<<512, 256, 0, stream>>>(Qp, Kp, q2, k2, 65536);
      attn3<<<dim3(16, 16, 2), 512, 0, stream>>>(Qp, Kp, Vtp, q2, k2, attAll);
      gemm_out_bf<<<dim3(8, 32), 256, 0, stream>>>(attAll, Wob, bo, out);
    } else {
      for (int b = 0; b < 2; ++b)
        gemm_qkvp<<<dim3(24, 16), 256, 0, stream>>>(
            x + (size_t)b * 2097152, wq, bq, wk, bk, wv, bv,
            Qp + (size_t)b * 2097152, Kp + (size_t)b * 2097152,
            Vtp + (size_t)b * 2097152, 0, 8);
      sumsq<<<512, 256, 0, stream>>>(Qp, Kp, q2, k2, 65536);
      attn3<<<dim3(16, 16, 2), 512, 0, stream>>>(Qp, Kp, Vtp, q2, k2, attAll);
      gemm_out_ws<<<dim3(8, 32), 256, 0, stream>>>(attAll, wo, bo, out);
    }
  } else {
    // Tier C: small-ws fallback (att fp32 in d_out, in-place outproj).
    int G = 16;
    while (G > 2 && (size_t)G * 802816ULL > ws_size) G >>= 1;
    short* Qp = (short*)d_ws;
    short* Kp = Qp + (size_t)G * 131072;
    short* Vtp = Kp + (size_t)G * 131072;
    float* q2 = (float*)(Vtp + (size_t)G * 131072);
    float* k2 = q2 + (size_t)G * 2048;

    const int groups = 16 / G;
    for (int b = 0; b < 2; ++b) {
      const float* xb = x + (size_t)b * 2097152;
      float* attB = out + (size_t)b * 2097152;
      for (int g = 0; g < groups; ++g) {
        gemm_qkvp<<<dim3(3 * (G / 2), 16), 256, 0, stream>>>(
            xb, wq, bq, wk, bk, wv, bv, Qp, Kp, Vtp, g * G * 64, G / 2);
        sumsq<<<16 * G, 256, 0, stream>>>(Qp, Kp, q2, k2, G * 2048);
        attn_c<<<dim3(32, G), 256, 0, stream>>>(Qp, Kp, Vtp, q2, k2, attB,
                                                g * G * 64);
      }
    }
    outproj_inplace<<<256, 256, 0, stream>>>(out, wo, bo);
  }
}

// Round 12
// 228.286 us; speedup vs baseline: 3.2292x; 1.1518x over previous
//
#include <hip/hip_runtime.h>

// L2 self-attention. Inputs/outputs FP32; compute bf16 MFMA, fp32 accumulate.
// B=2 N=2048 D=1024 H=16 hd=64.
// R12: batch-fused QKV GEMM (768 blocks, 3/CU), 64x128-tile out-projection
// (512 blocks, 2/CU vs 256 at 1/CU), weight-cvt fused to one launch.
// attn3: LDS-staged flash attention, fixed softmax max=0, raw v_sqrt, 2-op
// half-up f2bf. Tier A2 (ws>=48.5MB): bf16-preconverted GEMMs (GLDS16 both
// operands). Tier A (>=32.5MB): fp32 pack8 staging. Tier C: small-ws fallback.

typedef __attribute__((ext_vector_type(8))) short sh8;   // 8 bf16 (4 VGPRs)
typedef __attribute__((ext_vector_type(4))) short sh4;   // 4 bf16 (2 VGPRs)
typedef __attribute__((ext_vector_type(4))) float f4;    // 4 fp32

__device__ __forceinline__ float bf2f(short s) {
  union { unsigned u; float f; } c;
  c.u = ((unsigned)(unsigned short)s) << 16;
  return c.f;
}
// fast bf16 round: half-up (2 VALU ops); <=1 ulp vs RNE, budget 2.4e-3.
__device__ __forceinline__ short f2bf(float f) {
  union { float f; unsigned u; } c;
  c.f = f;
  return (short)((c.u + 0x8000u) >> 16);
}
__device__ __forceinline__ sh8 pack8(f4 a, f4 b) {
  sh8 r;
  r[0] = f2bf(a[0]); r[1] = f2bf(a[1]); r[2] = f2bf(a[2]); r[3] = f2bf(a[3]);
  r[4] = f2bf(b[0]); r[5] = f2bf(b[1]); r[6] = f2bf(b[2]); r[7] = f2bf(b[3]);
  return r;
}

// async global->LDS, 16B per lane; LDS dest = wave-uniform base + lane*16
#define GLDS16(g, l)                                                      \
  __builtin_amdgcn_global_load_lds(                                       \
      (__attribute__((address_space(1))) void*)(void*)(g),                \
      (__attribute__((address_space(3))) void*)(void*)(l), 16, 0, 0)

// ---------------------------------------------------------------------------
// fp32 -> bf16 elementwise (n multiple of 8)
// ---------------------------------------------------------------------------
__global__ __launch_bounds__(256) void cvt_bf16(const float* __restrict__ src,
                                                short* __restrict__ dst, int n) {
  const int i = (blockIdx.x * 256 + threadIdx.x) * 8;
  if (i < n)
    *(sh8*)(dst + i) = pack8(*(const f4*)(src + i), *(const f4*)(src + i + 4));
}

// 4 weight matrices (1M elems each) -> contiguous bf16 dst, one launch.
__global__ __launch_bounds__(256) void cvt_w4(
    const float* __restrict__ wq, const float* __restrict__ wk,
    const float* __restrict__ wv, const float* __restrict__ wo,
    short* __restrict__ dst) {
  const float* srcs[4] = {wq, wk, wv, wo};
  const float* s = srcs[blockIdx.y];
  short* d = dst + (size_t)blockIdx.y * 1048576;
  const int i = (blockIdx.x * 256 + threadIdx.x) * 8;
  *(sh8*)(d + i) = pack8(*(const f4*)(s + i), *(const f4*)(s + i + 4));
}

// ---------------------------------------------------------------------------
// QKV projection, fp32 inputs, batch-fused (M=4096 when grid.y=32).
// Epilogue: batch = m>>11, head slot = batch*16 + hl. (Tier C: m<2048 -> 0.)
// ---------------------------------------------------------------------------
__global__ __launch_bounds__(256) void gemm_qkvp(
    const float* __restrict__ X, const float* __restrict__ Wq,
    const float* __restrict__ Bq, const float* __restrict__ Wk,
    const float* __restrict__ Bk, const float* __restrict__ Wv,
    const float* __restrict__ Bv, short* __restrict__ Qp,
    short* __restrict__ Kp, short* __restrict__ Vtp, int w0, int nblkP) {
  __shared__ short As[128 * 32];
  __shared__ short Bs[128 * 32];
  const int t = threadIdx.x;
  const int wave = t >> 6;
  const int lane = t & 63;
  const int l15 = lane & 15;
  const int quad = lane >> 4;
  const int m0 = blockIdx.y * 128;
  const int which = blockIdx.x / nblkP;
  const int n0l = (blockIdx.x % nblkP) * 128;
  const int wrow0 = w0 + n0l;
  const float* W = (which == 0) ? Wq : ((which == 1) ? Wk : Wv);
  const float* Bias = (which == 0) ? Bq : ((which == 1) ? Bk : Bv);
  const int wm = (wave & 1) * 64;
  const int wn = (wave >> 1) * 64;

  f4 acc[4][4];
#pragma unroll
  for (int i = 0; i < 4; ++i)
#pragma unroll
    for (int j = 0; j < 4; ++j) acc[i][j] = (f4){0.f, 0.f, 0.f, 0.f};

  const float* ag = X + (size_t)(m0 + (t >> 2)) * 1024 + (t & 3) * 8;
  const float* bg = W + (size_t)(wrow0 + (t >> 2)) * 1024 + (t & 3) * 8;

  for (int kt = 0; kt < 1024; kt += 32) {
    const sh8 a0 = pack8(*(const f4*)(ag + kt), *(const f4*)(ag + kt + 4));
    const sh8 a1 =
        pack8(*(const f4*)(ag + 65536 + kt), *(const f4*)(ag + 65536 + kt + 4));
    const sh8 b0 = pack8(*(const f4*)(bg + kt), *(const f4*)(bg + kt + 4));
    const sh8 b1 =
        pack8(*(const f4*)(bg + 65536 + kt), *(const f4*)(bg + 65536 + kt + 4));
    __syncthreads();
    *(sh8*)(As + t * 8) = a0;
    *(sh8*)(As + 2048 + t * 8) = a1;
    *(sh8*)(Bs + t * 8) = b0;
    *(sh8*)(Bs + 2048 + t * 8) = b1;
    __syncthreads();
    sh8 af[4], bf[4];
#pragma unroll
    for (int i = 0; i < 4; ++i) {
      af[i] = *(const sh8*)(As + (wm + i * 16 + l15) * 32 + quad * 8);
      bf[i] = *(const sh8*)(Bs + (wn + i * 16 + l15) * 32 + quad * 8);
    }
#pragma unroll
    for (int i = 0; i < 4; ++i)
#pragma unroll
      for (int j = 0; j < 4; ++j)
        acc[i][j] =
            __builtin_amdgcn_mfma_f32_16x16x32_bf16(af[i], bf[j], acc[i][j], 0, 0, 0);
  }

#pragma unroll
  for (int j = 0; j < 4; ++j) {
    const int ngl = n0l + wn + j * 16 + l15;
    const float bias = Bias[w0 + ngl];
    const int hl = ngl >> 6;
    const int d = ngl & 63;
#pragma unroll
    for (int i = 0; i < 4; ++i) {
#pragma unroll
      for (int r = 0; r < 4; ++r) {
        const int m = m0 + wm + i * 16 + quad * 4 + r;
        const int slot = (m >> 11) * 16 + hl;   // batch*16 + head
        const int mm = m & 2047;
        const short o = f2bf(acc[i][j][r] + bias);
        if (which == 0)
          Qp[((size_t)slot * 2048 + mm) * 64 + d] = o;
        else if (which == 1)
          Kp[((size_t)slot * 2048 + mm) * 64 + d] = o;
        else
          Vtp[((size_t)slot * 64 + d) * 2048 + mm] = o;
      }
    }
  }
}

// ---------------------------------------------------------------------------
// QKV projection, bf16 inputs (Tier A2), batch-fused: GLDS16 both operands.
// ---------------------------------------------------------------------------
__global__ __launch_bounds__(256) void gemm_qkv_bf(
    const short* __restrict__ X, const short* __restrict__ Wq,
    const float* __restrict__ Bq, const short* __restrict__ Wk,
    const float* __restrict__ Bk, const short* __restrict__ Wv,
    const float* __restrict__ Bv, short* __restrict__ Qp,
    short* __restrict__ Kp, short* __restrict__ Vtp) {
  __shared__ short As[128 * 32];
  __shared__ short Bs[128 * 32];
  const int t = threadIdx.x;
  const int wave = t >> 6;
  const int lane = t & 63;
  const int l15 = lane & 15;
  const int quad = lane >> 4;
  const int m0 = blockIdx.y * 128;       // [0,4096)
  const int which = blockIdx.x >> 3;     // 0=Q 1=K 2=V
  const int n0l = (blockIdx.x & 7) * 128;
  const short* W = (which == 0) ? Wq : ((which == 1) ? Wk : Wv);
  const float* Bias = (which == 0) ? Bq : ((which == 1) ? Bk : Bv);
  const int wm = (wave & 1) * 64;
  const int wn = (wave >> 1) * 64;

  f4 acc[4][4];
#pragma unroll
  for (int i = 0; i < 4; ++i)
#pragma unroll
    for (int j = 0; j < 4; ++j) acc[i][j] = (f4){0.f, 0.f, 0.f, 0.f};

  const short* ag = X + (size_t)(m0 + (t >> 2)) * 1024 + (t & 3) * 8;
  const short* bg = W + (size_t)(n0l + (t >> 2)) * 1024 + (t & 3) * 8;
  short* al = As + wave * 512;
  short* bl = Bs + wave * 512;

  for (int kt = 0; kt < 1024; kt += 32) {
    __syncthreads();
    GLDS16(ag + kt, al);
    GLDS16(ag + 65536 + kt, al + 2048);
    GLDS16(bg + kt, bl);
    GLDS16(bg + 65536 + kt, bl + 2048);
    __syncthreads();
    sh8 af[4], bf[4];
#pragma unroll
    for (int i = 0; i < 4; ++i) {
      af[i] = *(const sh8*)(As + (wm + i * 16 + l15) * 32 + quad * 8);
      bf[i] = *(const sh8*)(Bs + (wn + i * 16 + l15) * 32 + quad * 8);
    }
#pragma unroll
    for (int i = 0; i < 4; ++i)
#pragma unroll
      for (int j = 0; j < 4; ++j)
        acc[i][j] =
            __builtin_amdgcn_mfma_f32_16x16x32_bf16(af[i], bf[j], acc[i][j], 0, 0, 0);
  }

#pragma unroll
  for (int j = 0; j < 4; ++j) {
    const int ngl = n0l + wn + j * 16 + l15;
    const float bias = Bias[ngl];
    const int hl = ngl >> 6;
    const int d = ngl & 63;
#pragma unroll
    for (int i = 0; i < 4; ++i) {
#pragma unroll
      for (int r = 0; r < 4; ++r) {
        const int m = m0 + wm + i * 16 + quad * 4 + r;
        const int slot = (m >> 11) * 16 + hl;
        const int mm = m & 2047;
        const short o = f2bf(acc[i][j][r] + bias);
        if (which == 0)
          Qp[((size_t)slot * 2048 + mm) * 64 + d] = o;
        else if (which == 1)
          Kp[((size_t)slot * 2048 + mm) * 64 + d] = o;
        else
          Vtp[((size_t)slot * 64 + d) * 2048 + mm] = o;
      }
    }
  }
}

// ---------------------------------------------------------------------------
// Sums of squares of bf16-rounded Q and K rows. R rows per tensor.
// ---------------------------------------------------------------------------
__global__ __launch_bounds__(256) void sumsq(const short* __restrict__ Qp,
                                             const short* __restrict__ Kp,
                                             float* __restrict__ q2a,
                                             float* __restrict__ k2a, int R) {
  const int tid = blockIdx.x * 256 + threadIdx.x;
  const bool isQ = tid < R;
  const int r = isQ ? tid : tid - R;
  const short* p = (isQ ? Qp : Kp) + (size_t)r * 64;
  float s = 0.f;
#pragma unroll
  for (int i = 0; i < 8; ++i) {
    sh8 v = *(const sh8*)(p + i * 8);
#pragma unroll
    for (int j = 0; j < 8; ++j) {
      float f = bf2f(v[j]);
      s = fmaf(f, f, s);
    }
  }
  (isQ ? q2a : k2a)[r] = s;
}

// ---------------------------------------------------------------------------
// attn3: LDS-staged flash attention, fixed max=0. Block = 8 waves = 128
// queries; K/V tiles of 128 staged to LDS (strides 72/136). Wave owns 16 q.
// S^T = MFMA(A=Kfrag, B=Qfrag): C row=key(quad*4+r), col=query(l15) ==
// A-layout of P for 16x16x16 PV. O C-layout: row=query, col=vdim chunk.
// ---------------------------------------------------------------------------
__global__ __launch_bounds__(512, 4) void attn3(
    const short* __restrict__ Qp, const short* __restrict__ Kp,
    const short* __restrict__ Vtp, const float* __restrict__ q2a,
    const float* __restrict__ k2a, short* __restrict__ attH) {
  __shared__ short Ks[128 * 72];   // 18 KB
  __shared__ short Vs[64 * 136];   // 17 KB
  const int t = threadIdx.x;
  const int wave = t >> 6;
  const int lane = t & 63;
  const int l15 = lane & 15;
  const int quad = lane >> 4;
  const int hy = blockIdx.y;
  const int qt = blockIdx.x;
  const int bz = blockIdx.z;
  const size_t hb = (size_t)bz * gridDim.y + hy;
  const size_t base = hb * 2048;
  const int qrow = qt * 128 + wave * 16 + l15;

  const short* qp = Qp + (base + qrow) * 64 + quad * 8;
  const sh8 qf0 = *(const sh8*)qp;
  const sh8 qf1 = *(const sh8*)(qp + 32);
  const float q2 = q2a[base + qrow];

  float l_run = 0.f;
  f4 o0 = (f4){0.f, 0.f, 0.f, 0.f}, o1 = o0, o2 = o0, o3 = o0;

  const float* k2p = k2a + base + quad * 4;

  for (int k0 = 0; k0 < 2048; k0 += 128) {
    sh8 kv0, kv1, vv0, vv1;
    {
      const short* kg = Kp + (base + k0 + (t >> 3)) * 64 + (t & 7) * 8;
      kv0 = *(const sh8*)kg;
      kv1 = *(const sh8*)(kg + 64 * 64);
      const short* vg =
          Vtp + (hb * 64 + (t >> 4)) * 2048 + k0 + (t & 15) * 8;
      vv0 = *(const sh8*)vg;
      vv1 = *(const sh8*)(vg + 32 * 2048);
    }
    __syncthreads();
    *(sh8*)(Ks + (t >> 3) * 72 + (t & 7) * 8) = kv0;
    *(sh8*)(Ks + (64 + (t >> 3)) * 72 + (t & 7) * 8) = kv1;
    *(sh8*)(Vs + (t >> 4) * 136 + (t & 15) * 8) = vv0;
    *(sh8*)(Vs + (32 + (t >> 4)) * 136 + (t & 15) * 8) = vv1;
    __syncthreads();

#pragma unroll
    for (int sub = 0; sub < 8; ++sub) {
      const int j = sub * 16;
      const sh8 kf0 = *(const sh8*)(Ks + (j + l15) * 72 + quad * 8);
      const sh8 kf1 = *(const sh8*)(Ks + (j + l15) * 72 + 32 + quad * 8);
      f4 st = (f4){0.f, 0.f, 0.f, 0.f};
      st = __builtin_amdgcn_mfma_f32_16x16x32_bf16(kf0, qf0, st, 0, 0, 0);
      st = __builtin_amdgcn_mfma_f32_16x16x32_bf16(kf1, qf1, st, 0, 0, 0);
      const f4 k2v = *(const f4*)(k2p + k0 + j);
      float p[4];
#pragma unroll
      for (int r = 0; r < 4; ++r) {
        const float d2 = fmaxf(fmaf(-2.f, st[r], q2 + k2v[r]), 1e-12f);
        p[r] = __expf(-__builtin_amdgcn_sqrtf(d2));
      }
      l_run += (p[0] + p[1]) + (p[2] + p[3]);
      sh4 pf;
#pragma unroll
      for (int r = 0; r < 4; ++r) pf[r] = f2bf(p[r]);
      const sh4 vf0 = *(const sh4*)(Vs + l15 * 136 + j + quad * 4);
      const sh4 vf1 = *(const sh4*)(Vs + (l15 + 16) * 136 + j + quad * 4);
      const sh4 vf2 = *(const sh4*)(Vs + (l15 + 32) * 136 + j + quad * 4);
      const sh4 vf3 = *(const sh4*)(Vs + (l15 + 48) * 136 + j + quad * 4);
      o0 = __builtin_amdgcn_mfma_f32_16x16x16bf16_1k(pf, vf0, o0, 0, 0, 0);
      o1 = __builtin_amdgcn_mfma_f32_16x16x16bf16_1k(pf, vf1, o1, 0, 0, 0);
      o2 = __builtin_amdgcn_mfma_f32_16x16x16bf16_1k(pf, vf2, o2, 0, 0, 0);
      o3 = __builtin_amdgcn_mfma_f32_16x16x16bf16_1k(pf, vf3, o3, 0, 0, 0);
    }
  }

  l_run += __shfl_xor(l_run, 16);
  l_run += __shfl_xor(l_run, 32);
  const float il0 = 1.f / __shfl(l_run, quad * 4 + 0);
  const float il1 = 1.f / __shfl(l_run, quad * 4 + 1);
  const float il2 = 1.f / __shfl(l_run, quad * 4 + 2);
  const float il3 = 1.f / __shfl(l_run, quad * 4 + 3);

  const int rowbase = qt * 128 + wave * 16 + quad * 4;
  const f4* oc[4] = {&o0, &o1, &o2, &o3};
  const float il[4] = {il0, il1, il2, il3};
  const size_t off0 = ((size_t)bz * 2048 + rowbase) * 1024 + hy * 64 + l15;
#pragma unroll
  for (int c = 0; c < 4; ++c)
#pragma unroll
    for (int r = 0; r < 4; ++r)
      attH[off0 + (size_t)r * 1024 + c * 16] = f2bf((*oc[c])[r] * il[r]);
}

// ---------------------------------------------------------------------------
// attn (global-load variant) for Tier C only: fp32 att into d_out slice.
// ---------------------------------------------------------------------------
__global__ __launch_bounds__(256) void attn_c(
    const short* __restrict__ Qp, const short* __restrict__ Kp,
    const short* __restrict__ Vtp, const float* __restrict__ q2a,
    const float* __restrict__ k2a, float* __restrict__ attF, int col0) {
  const int t = threadIdx.x;
  const int wave = t >> 6;
  const int lane = t & 63;
  const int l15 = lane & 15;
  const int quad = lane >> 4;
  const int hy = blockIdx.y;
  const int qt = blockIdx.x;
  const size_t base = (size_t)hy * 2048;
  const int qrow = qt * 64 + wave * 16 + l15;

  const short* qp = Qp + (base + qrow) * 64 + quad * 8;
  const sh8 qf0 = *(const sh8*)qp;
  const sh8 qf1 = *(const sh8*)(qp + 32);
  const float q2 = q2a[base + qrow];

  float l_run = 0.f;
  f4 o0 = (f4){0.f, 0.f, 0.f, 0.f}, o1 = o0, o2 = o0, o3 = o0;

  const short* kbase = Kp + (base + l15) * 64 + quad * 8;
  const float* k2p = k2a + base + quad * 4;
  const short* vbase = Vtp + ((size_t)hy * 64 + l15) * 2048 + quad * 4;

  for (int j = 0; j < 2048; j += 16) {
    const sh8 kf0 = *(const sh8*)(kbase + (size_t)j * 64);
    const sh8 kf1 = *(const sh8*)(kbase + (size_t)j * 64 + 32);
    f4 st = (f4){0.f, 0.f, 0.f, 0.f};
    st = __builtin_amdgcn_mfma_f32_16x16x32_bf16(kf0, qf0, st, 0, 0, 0);
    st = __builtin_amdgcn_mfma_f32_16x16x32_bf16(kf1, qf1, st, 0, 0, 0);
    const f4 k2v = *(const f4*)(k2p + j);
    float p[4];
#pragma unroll
    for (int r = 0; r < 4; ++r) {
      const float d2 = fmaxf(fmaf(-2.f, st[r], q2 + k2v[r]), 1e-12f);
      p[r] = __expf(-__builtin_amdgcn_sqrtf(d2));
    }
    l_run += (p[0] + p[1]) + (p[2] + p[3]);
    sh4 pf;
#pragma unroll
    for (int r = 0; r < 4; ++r) pf[r] = f2bf(p[r]);
    const sh4 vf0 = *(const sh4*)(vbase + j);
    const sh4 vf1 = *(const sh4*)(vbase + 16 * 2048 + j);
    const sh4 vf2 = *(const sh4*)(vbase + 32 * 2048 + j);
    const sh4 vf3 = *(const sh4*)(vbase + 48 * 2048 + j);
    o0 = __builtin_amdgcn_mfma_f32_16x16x16bf16_1k(pf, vf0, o0, 0, 0, 0);
    o1 = __builtin_amdgcn_mfma_f32_16x16x16bf16_1k(pf, vf1, o1, 0, 0, 0);
    o2 = __builtin_amdgcn_mfma_f32_16x16x16bf16_1k(pf, vf2, o2, 0, 0, 0);
    o3 = __builtin_amdgcn_mfma_f32_16x16x16bf16_1k(pf, vf3, o3, 0, 0, 0);
  }

  l_run += __shfl_xor(l_run, 16);
  l_run += __shfl_xor(l_run, 32);
  const float il0 = 1.f / __shfl(l_run, quad * 4 + 0);
  const float il1 = 1.f / __shfl(l_run, quad * 4 + 1);
  const float il2 = 1.f / __shfl(l_run, quad * 4 + 2);
  const float il3 = 1.f / __shfl(l_run, quad * 4 + 3);

  const int rowbase = qt * 64 + wave * 16 + quad * 4;
  const f4* oc[4] = {&o0, &o1, &o2, &o3};
  const float il[4] = {il0, il1, il2, il3};
  const size_t off0 = (size_t)rowbase * 1024 + col0 + hy * 64 + l15;
#pragma unroll
  for (int c = 0; c < 4; ++c)
#pragma unroll
    for (int r = 0; r < 4; ++r)
      attF[off0 + (size_t)r * 1024 + c * 16] = (*oc[c])[r] * il[r];
}

// ---------------------------------------------------------------------------
// Output projection, 64x128 tile (512 blocks = 2/CU). Tier A2: bf16 Wo.
// Wave tile 32x64: acc[2][4].
// ---------------------------------------------------------------------------
__global__ __launch_bounds__(256) void gemm_out_bf64(
    const short* __restrict__ A, const short* __restrict__ W,
    const float* __restrict__ Bias, float* __restrict__ Out) {
  __shared__ short As[64 * 32];
  __shared__ short Bs[128 * 32];
  const int t = threadIdx.x;
  const int wave = t >> 6;
  const int lane = t & 63;
  const int l15 = lane & 15;
  const int quad = lane >> 4;
  const int m0 = blockIdx.y * 64;
  const int n0 = blockIdx.x * 128;
  const int wm = (wave & 1) * 32;
  const int wn = (wave >> 1) * 64;

  f4 acc[2][4];
#pragma unroll
  for (int i = 0; i < 2; ++i)
#pragma unroll
    for (int j = 0; j < 4; ++j) acc[i][j] = (f4){0.f, 0.f, 0.f, 0.f};

  const short* ag = A + (size_t)(m0 + (t >> 2)) * 1024 + (t & 3) * 8;
  const short* bg = W + (size_t)(n0 + (t >> 2)) * 1024 + (t & 3) * 8;
  short* al = As + wave * 512;
  short* bl = Bs + wave * 512;

  for (int kt = 0; kt < 1024; kt += 32) {
    __syncthreads();
    GLDS16(ag + kt, al);          // A: 64x32 = one issue
    GLDS16(bg + kt, bl);          // B: 128x32 = two issues
    GLDS16(bg + 65536 + kt, bl + 2048);
    __syncthreads();
    sh8 af[2], bf[4];
#pragma unroll
    for (int i = 0; i < 2; ++i)
      af[i] = *(const sh8*)(As + (wm + i * 16 + l15) * 32 + quad * 8);
#pragma unroll
    for (int j = 0; j < 4; ++j)
      bf[j] = *(const sh8*)(Bs + (wn + j * 16 + l15) * 32 + quad * 8);
#pragma unroll
    for (int i = 0; i < 2; ++i)
#pragma unroll
      for (int j = 0; j < 4; ++j)
        acc[i][j] =
            __builtin_amdgcn_mfma_f32_16x16x32_bf16(af[i], bf[j], acc[i][j], 0, 0, 0);
  }

#pragma unroll
  for (int j = 0; j < 4; ++j) {
    const int n = n0 + wn + j * 16 + l15;
    const float bias = Bias[n];
#pragma unroll
    for (int i = 0; i < 2; ++i) {
#pragma unroll
      for (int r = 0; r < 4; ++r) {
        const int m = m0 + wm + i * 16 + quad * 4 + r;
        Out[(size_t)m * 1024 + n] = acc[i][j][r] + bias;
      }
    }
  }
}

// Tier A variant: fp32 Wo with pack8 staging, same 64x128 tile.
__global__ __launch_bounds__(256) void gemm_out_ws64(
    const short* __restrict__ A, const float* __restrict__ W,
    const float* __restrict__ Bias, float* __restrict__ Out) {
  __shared__ short As[64 * 32];
  __shared__ short Bs[128 * 32];
  const int t = threadIdx.x;
  const int wave = t >> 6;
  const int lane = t & 63;
  const int l15 = lane & 15;
  const int quad = lane >> 4;
  const int m0 = blockIdx.y * 64;
  const int n0 = blockIdx.x * 128;
  const int wm = (wave & 1) * 32;
  const int wn = (wave >> 1) * 64;

  f4 acc[2][4];
#pragma unroll
  for (int i = 0; i < 2; ++i)
#pragma unroll
    for (int j = 0; j < 4; ++j) acc[i][j] = (f4){0.f, 0.f, 0.f, 0.f};

  const short* ag = A + (size_t)(m0 + (t >> 2)) * 1024 + (t & 3) * 8;
  const float* bg = W + (size_t)(n0 + (t >> 2)) * 1024 + (t & 3) * 8;
  short* al = As + wave * 512;

  for (int kt = 0; kt < 1024; kt += 32) {
    const sh8 b0 = pack8(*(const f4*)(bg + kt), *(const f4*)(bg + kt + 4));
    const sh8 b1 =
        pack8(*(const f4*)(bg + 65536 + kt), *(const f4*)(bg + 65536 + kt + 4));
    __syncthreads();
    GLDS16(ag + kt, al);
    *(sh8*)(Bs + t * 8) = b0;
    *(sh8*)(Bs + 2048 + t * 8) = b1;
    __syncthreads();
    sh8 af[2], bf[4];
#pragma unroll
    for (int i = 0; i < 2; ++i)
      af[i] = *(const sh8*)(As + (wm + i * 16 + l15) * 32 + quad * 8);
#pragma unroll
    for (int j = 0; j < 4; ++j)
      bf[j] = *(const sh8*)(Bs + (wn + j * 16 + l15) * 32 + quad * 8);
#pragma unroll
    for (int i = 0; i < 2; ++i)
#pragma unroll
      for (int j = 0; j < 4; ++j)
        acc[i][j] =
            __builtin_amdgcn_mfma_f32_16x16x32_bf16(af[i], bf[j], acc[i][j], 0, 0, 0);
  }

#pragma unroll
  for (int j = 0; j < 4; ++j) {
    const int n = n0 + wn + j * 16 + l15;
    const float bias = Bias[n];
#pragma unroll
    for (int i = 0; i < 2; ++i) {
#pragma unroll
      for (int r = 0; r < 4; ++r) {
        const int m = m0 + wm + i * 16 + quad * 4 + r;
        Out[(size_t)m * 1024 + n] = acc[i][j][r] + bias;
      }
    }
  }
}

// ---------------------------------------------------------------------------
// Fallback in-place output projection (Tier C).
// ---------------------------------------------------------------------------
__global__ __launch_bounds__(256) void outproj_inplace(
    float* __restrict__ AO, const float* __restrict__ W,
    const float* __restrict__ Bias) {
  __shared__ short attS[16 * 264];
  const int t = threadIdx.x;
  const int wave = t >> 6;
  const int lane = t & 63;
  const int l15 = lane & 15;
  const int quad = lane >> 4;
  const int m0 = blockIdx.x * 16;
  const int n0w = wave * 256;

  f4 acc[16];
#pragma unroll
  for (int i = 0; i < 16; ++i) acc[i] = (f4){0.f, 0.f, 0.f, 0.f};

  for (int kc = 0; kc < 4; ++kc) {
    __syncthreads();
#pragma unroll
    for (int i = 0; i < 2; ++i) {
      const int e = i * 2048 + t * 8;
      const int row = e >> 8;
      const int col = e & 255;
      const float* src = AO + (size_t)(m0 + row) * 1024 + kc * 256 + col;
      *(sh8*)(attS + row * 264 + col) =
          pack8(*(const f4*)src, *(const f4*)(src + 4));
    }
    __syncthreads();
    for (int ktl = 0; ktl < 256; ktl += 32) {
      const sh8 af = *(const sh8*)(attS + l15 * 264 + ktl + quad * 8);
      const int kt = kc * 256 + ktl;
#pragma unroll
      for (int nf = 0; nf < 16; ++nf) {
        const float* wp = W + (size_t)(n0w + nf * 16 + l15) * 1024 + kt + quad * 8;
        const sh8 bf = pack8(*(const f4*)wp, *(const f4*)(wp + 4));
        acc[nf] = __builtin_amdgcn_mfma_f32_16x16x32_bf16(af, bf, acc[nf], 0, 0, 0);
      }
    }
  }
  __syncthreads();

#pragma unroll
  for (int nf = 0; nf < 16; ++nf) {
    const int n = n0w + nf * 16 + l15;
    const float bias = Bias[n];
#pragma unroll
    for (int r = 0; r < 4; ++r) {
      const int m = m0 + quad * 4 + r;
      AO[(size_t)m * 1024 + n] = acc[nf][r] + bias;
    }
  }
}

// ---------------------------------------------------------------------------
extern "C" void kernel_launch(void* const* d_in, const int* in_sizes, int n_in,
                              void* d_out, int out_size, void* d_ws,
                              size_t ws_size, hipStream_t stream) {
  const float* x = (const float*)d_in[0];
  const float* wq = (const float*)d_in[1];
  const float* bq = (const float*)d_in[2];
  const float* wk = (const float*)d_in[3];
  const float* bk = (const float*)d_in[4];
  const float* wv = (const float*)d_in[5];
  const float* bv = (const float*)d_in[6];
  const float* wo = (const float*)d_in[7];
  const float* bo = (const float*)d_in[8];
  float* out = (float*)d_out;

  const size_t NEED_A2 = 50855936ULL;  // A + Xbf 8MB + Wbf 8MB
  const size_t NEED_A = 34078720ULL;   // 24MB QKV(2b) + 8MB att + 512KB q2k2

  if (ws_size >= NEED_A) {
    short* Qp = (short*)d_ws;                 // [b*16+h][2048][64] bf16, 8MB
    short* Kp = Qp + 4194304;                 // 8MB
    short* Vtp = Kp + 4194304;                // [b*16+h][64][2048] bf16, 8MB
    short* attAll = Vtp + 4194304;            // [4096][1024] bf16, 8MB
    float* q2 = (float*)(attAll + 4194304);   // 256KB
    float* k2 = q2 + 65536;                   // 256KB

    if (ws_size >= NEED_A2) {
      short* Xb = (short*)(k2 + 65536);       // 4M bf16 = 8MB
      short* Wqb = Xb + 4194304;              // 4x 1M bf16, contiguous
      cvt_bf16<<<2048, 256, 0, stream>>>(x, Xb, 4194304);
      cvt_w4<<<dim3(512, 4), 256, 0, stream>>>(wq, wk, wv, wo, Wqb);
      gemm_qkv_bf<<<dim3(24, 32), 256, 0, stream>>>(
          Xb, Wqb, bq, Wqb + 1048576, bk, Wqb + 2097152, bv, Qp, Kp, Vtp);
      sumsq<<<512, 256, 0, stream>>>(Qp, Kp, q2, k2, 65536);
      attn3<<<dim3(16, 16, 2), 512, 0, stream>>>(Qp, Kp, Vtp, q2, k2, attAll);
      gemm_out_bf64<<<dim3(8, 64), 256, 0, stream>>>(attAll, Wqb + 3145728,
                                                     bo, out);
    } else {
      gemm_qkvp<<<dim3(24, 32), 256, 0, stream>>>(x, wq, bq, wk, bk, wv, bv,
                                                  Qp, Kp, Vtp, 0, 8);
      sumsq<<<512, 256, 0, stream>>>(Qp, Kp, q2, k2, 65536);
      attn3<<<dim3(16, 16, 2), 512, 0, stream>>>(Qp, Kp, Vtp, q2, k2, attAll);
      gemm_out_ws64<<<dim3(8, 64), 256, 0, stream>>>(attAll, wo, bo, out);
    }
  } else {
    // Tier C: small-ws fallback (att fp32 in d_out, in-place outproj).
    int G = 16;
    while (G > 2 && (size_t)G * 802816ULL > ws_size) G >>= 1;
    short* Qp = (short*)d_ws;
    short* Kp = Qp + (size_t)G * 131072;
    short* Vtp = Kp + (size_t)G * 131072;
    float* q2 = (float*)(Vtp + (size_t)G * 131072);
    float* k2 = q2 + (size_t)G * 2048;

    const int groups = 16 / G;
    for (int b = 0; b < 2; ++b) {
      const float* xb = x + (size_t)b * 2097152;
      float* attB = out + (size_t)b * 2097152;
      for (int g = 0; g < groups; ++g) {
        gemm_qkvp<<<dim3(3 * (G / 2), 16), 256, 0, stream>>>(
            xb, wq, bq, wk, bk, wv, bv, Qp, Kp, Vtp, g * G * 64, G / 2);
        sumsq<<<16 * G, 256, 0, stream>>>(Qp, Kp, q2, k2, G * 2048);
        attn_c<<<dim3(32, G), 256, 0, stream>>>(Qp, Kp, Vtp, q2, k2, attB,
                                                g * G * 64);
      }
    }
    outproj_inplace<<<256, 256, 0, stream>>>(out, wo, bo);
  }
}